// Round 1
// baseline (285.061 us; speedup 1.0000x reference)
//
#include <hip/hip_runtime.h>
#include <math.h>

#define D_MODEL 1024
#define DK 64
#define DV 128
#define NH 8
#define BB 4
#define SQL 2048
#define SKV 2048

typedef __bf16 bf16x8 __attribute__((ext_vector_type(8)));
typedef float f32x4 __attribute__((ext_vector_type(4)));

#if __has_builtin(__builtin_amdgcn_exp2f)
#define EXP2(x) __builtin_amdgcn_exp2f(x)
#else
#define EXP2(x) exp2f(x)
#endif

#define MFMA16(a, b, c) __builtin_amdgcn_mfma_f32_16x16x32_bf16(a, b, c, 0, 0, 0)

// fp32 -> bf16 round-to-nearest-even
__device__ __forceinline__ ushort f2bf(float f) {
  unsigned u = __float_as_uint(f);
  u += 0x7FFFu + ((u >> 16) & 1u);
  return (ushort)(u >> 16);
}
// pack two fp32 -> bf16x2 (RNE both halves)
__device__ __forceinline__ unsigned pk2bf(float lo, float hi) {
  unsigned ul = __float_as_uint(lo);
  unsigned uh = __float_as_uint(hi);
  ul += 0x7FFFu + ((ul >> 16) & 1u);
  uh += 0x7FFFu + ((uh >> 16) & 1u);
  return __builtin_amdgcn_perm(uh, ul, 0x07060302u);
}

// async global->LDS, 16B per lane; dest = wave-uniform base + lane*16
#define GLDS16(g, l)                                                       \
  __builtin_amdgcn_global_load_lds(                                        \
      (const __attribute__((address_space(1))) unsigned int*)(g),          \
      (__attribute__((address_space(3))) unsigned int*)(l), 16, 0, 0)

// ---------------------------------------------------------------------------
// fp32 -> bf16 elementwise, two tensors in one dispatch (z selects)
// ---------------------------------------------------------------------------
__global__ __launch_bounds__(256) void cvt2_kernel(
    const float* __restrict__ s0, const float* __restrict__ s1,
    ushort* __restrict__ d0, ushort* __restrict__ d1, int n4) {
  const float* src = blockIdx.z ? s1 : s0;
  ushort* dst = blockIdx.z ? d1 : d0;
  int i = blockIdx.x * 256 + threadIdx.x;
  if (i >= n4) return;
  float4 v = ((const float4*)src)[i];
  ushort4 o;
  o.x = f2bf(v.x); o.y = f2bf(v.y); o.z = f2bf(v.z); o.w = f2bf(v.w);
  ((ushort4*)dst)[i] = o;
}

// ---------------------------------------------------------------------------
// Four weight transposes (fp32 [1024][C] -> bf16 [C][1024]) in one dispatch.
// ---------------------------------------------------------------------------
__global__ __launch_bounds__(256) void cvt_t4_kernel(
    const float* __restrict__ W0, const float* __restrict__ W1,
    const float* __restrict__ W2, const float* __restrict__ W3,
    ushort* __restrict__ T0, ushort* __restrict__ T1, ushort* __restrict__ T2,
    ushort* __restrict__ T3) {
  __shared__ ushort T[32][34];
  const int z = blockIdx.z;
  const int C = (z < 2) ? 512 : 1024;
  const int c0 = blockIdx.y * 32;
  if (c0 >= C) return;
  const float* W = (z == 0) ? W0 : (z == 1) ? W1 : (z == 2) ? W2 : W3;
  ushort* Wt = (z == 0) ? T0 : (z == 1) ? T1 : (z == 2) ? T2 : T3;
  const int R = 1024;
  const int r0 = blockIdx.x * 32;
  const int tx = threadIdx.x, ty = threadIdx.y;
#pragma unroll
  for (int i = 0; i < 4; ++i) {
    const int rr = ty + i * 8;
    T[rr][tx] = f2bf(W[(size_t)(r0 + rr) * C + c0 + tx]);
  }
  __syncthreads();
#pragma unroll
  for (int i = 0; i < 4; ++i) {
    const int rr = ty + i * 8;
    Wt[(size_t)(c0 + rr) * R + r0 + tx] = T[tx][rr];
  }
}

// ---------------------------------------------------------------------------
// GEMM core: acc[4][4] = Atile[128,K] @ Bttile[128,K]^T (per-wave 64x64).
// m97 global_load_lds staging, BK=32, XOR-swizzled LDS (2-way = free).
// ---------------------------------------------------------------------------
__device__ __forceinline__ void gemm_core_acc(ushort (*As)[32],
                                              ushort (*Bs)[32],
                                              const ushort* At,
                                              const ushort* Bt, int K,
                                              f32x4 (&acc)[4][4]) {
  const int t = threadIdx.x;
  const int w = t >> 6, lane = t & 63;
  const int wm = (w >> 1) * 64, wn = (w & 1) * 64;
  const int lr = lane & 15, quad = lane >> 4;

  const int r0 = t >> 2;
  const int lb = (t & 3) ^ ((r0 >> 1) & 3);
  const ushort* gA0 = At + (size_t)r0 * K + lb * 8;
  const ushort* gA1 = At + (size_t)(r0 + 64) * K + lb * 8;
  const ushort* gB0 = Bt + (size_t)r0 * K + lb * 8;
  const ushort* gB1 = Bt + (size_t)(r0 + 64) * K + lb * 8;
  ushort* dA0 = (ushort*)As + t * 8;
  ushort* dA1 = (ushort*)As + t * 8 + 2048;
  ushort* dB0 = (ushort*)Bs + t * 8;
  ushort* dB1 = (ushort*)Bs + t * 8 + 2048;

  const int sw = (quad ^ ((lr >> 1) & 3)) * 8;

#pragma unroll
  for (int i = 0; i < 4; ++i)
#pragma unroll
    for (int j = 0; j < 4; ++j) acc[i][j] = (f32x4){0.f, 0.f, 0.f, 0.f};

  for (int k0 = 0; k0 < K; k0 += 32) {
    __syncthreads();
    GLDS16(gA0 + k0, dA0);
    GLDS16(gA1 + k0, dA1);
    GLDS16(gB0 + k0, dB0);
    GLDS16(gB1 + k0, dB1);
    __syncthreads();
    bf16x8 fa[4], fb[4];
#pragma unroll
    for (int i = 0; i < 4; ++i) fa[i] = *(const bf16x8*)&As[wm + i * 16 + lr][sw];
#pragma unroll
    for (int j = 0; j < 4; ++j) fb[j] = *(const bf16x8*)&Bs[wn + j * 16 + lr][sw];
#pragma unroll
    for (int i = 0; i < 4; ++i)
#pragma unroll
      for (int j = 0; j < 4; ++j) acc[i][j] = MFMA16(fa[i], fb[j], acc[i][j]);
  }
}

// ---------------------------------------------------------------------------
// Fused QKV projection + v-transpose. WqkvT = [2048][1024] (WqT|WkT|WvT).
// grid (16, 64). n-region: q (direct, pre-scaled), k (direct),
// v (epilogue transposes 128skv x 128dv head-tile into vt[bh][dv][skv] via
// per-wave LDS stage; RNE packing — truncation bias would NOT cancel here).
// ---------------------------------------------------------------------------
__global__ __launch_bounds__(256) void gemm_qkv_kernel(
    const ushort* __restrict__ preb, const ushort* __restrict__ encb,
    const ushort* __restrict__ WqkvT, ushort* __restrict__ qb,
    ushort* __restrict__ kb, ushort* __restrict__ vt, float qsc) {
  __shared__ ushort shm[17408];  // union: staging 8192 | v-epilogue 17408
  ushort(*As)[32] = (ushort(*)[32])shm;
  ushort(*Bs)[32] = (ushort(*)[32])(shm + 4096);

  const int n0 = blockIdx.x * 128, m0 = blockIdx.y * 128;
  const int t = threadIdx.x;
  const int w = t >> 6, lane = t & 63;
  const int wm = (w >> 1) * 64, wn = (w & 1) * 64;
  const int lr = lane & 15, quad = lane >> 4;

  const ushort* A = (n0 < 512) ? preb : encb;
  f32x4 acc[4][4];
  gemm_core_acc(As, Bs, A + (size_t)m0 * D_MODEL, WqkvT + (size_t)n0 * D_MODEL,
                D_MODEL, acc);

  if (n0 < 1024) {
    ushort* C = (n0 < 512) ? qb : kb;
    const int ncol = (n0 < 512) ? n0 : n0 - 512;
    const float osc = (n0 < 512) ? qsc : 1.f;
#pragma unroll
    for (int i = 0; i < 4; ++i)
#pragma unroll
      for (int j = 0; j < 4; ++j)
#pragma unroll
        for (int r = 0; r < 4; ++r) {
          const int row = m0 + wm + i * 16 + quad * 4 + r;
          const int col = ncol + wn + j * 16 + lr;
          C[(size_t)row * 512 + col] = f2bf(acc[i][j][r] * osc);
        }
  } else {
    // v-region: tile = head h, batch b; write transposed into vt[bh][dv][skv]
    const int h = (n0 - 1024) >> 7;
    const int b = m0 >> 11;
    const int skv0 = m0 & 2047;
    __syncthreads();  // all waves done reading As/Bs
    ushort(*Ep)[68] = (ushort(*)[68])(shm + w * 4352);  // per-wave [dv64][skv64+4]
#pragma unroll
    for (int i = 0; i < 4; ++i)
#pragma unroll
      for (int j = 0; j < 4; ++j) {
        uint2 dd;
        dd.x = pk2bf(acc[i][j][0], acc[i][j][1]);
        dd.y = pk2bf(acc[i][j][2], acc[i][j][3]);
        *(uint2*)&Ep[j * 16 + lr][i * 16 + quad * 4] = dd;
      }
    // per-wave region: no barrier needed before reading own Ep
    ushort* vbase =
        vt + ((size_t)(b * NH + h) * DV + wn) * SKV + skv0 + wm;
#pragma unroll
    for (int rep = 0; rep < 8; ++rep) {
      const int dvl = (lane >> 3) + rep * 8;
      const int skvc = (lane & 7) * 8;
      *(uint4*)&vbase[(size_t)dvl * SKV + skvc] = *(const uint4*)&Ep[dvl][skvc];
    }
  }
}

// ---------------------------------------------------------------------------
// Output projection: out fp32 [8192][1024] = ao @ WoT^T. grid (8, 64).
// ---------------------------------------------------------------------------
__global__ __launch_bounds__(256) void gemm_o_kernel(
    const ushort* __restrict__ ao, const ushort* __restrict__ WoT,
    float* __restrict__ out) {
  __shared__ ushort As[128][32];
  __shared__ ushort Bs[128][32];
  const int n0 = blockIdx.x * 128, m0 = blockIdx.y * 128;
  const int t = threadIdx.x;
  const int w = t >> 6, lane = t & 63;
  const int wm = (w >> 1) * 64, wn = (w & 1) * 64;
  const int lr = lane & 15, quad = lane >> 4;
  f32x4 acc[4][4];
  gemm_core_acc(As, Bs, ao + (size_t)m0 * D_MODEL, WoT + (size_t)n0 * D_MODEL,
                D_MODEL, acc);
#pragma unroll
  for (int i = 0; i < 4; ++i)
#pragma unroll
    for (int j = 0; j < 4; ++j)
#pragma unroll
      for (int r = 0; r < 4; ++r) {
        const int row = m0 + wm + i * 16 + quad * 4 + r;
        const int col = n0 + wn + j * 16 + lr;
        out[(size_t)row * D_MODEL + col] = acc[i][j][r];
      }
}

// ---------------------------------------------------------------------------
// Attention, S^T formulation, KV-tile = 128 (2 barriers per 104 MFMA/wave vs
// per 52 before), processed as four 32-kv chunks with fine S->exp->PV
// interleave. Per-wave single-buffered P chunk (32q x 32kv); in-wave DS
// ordering makes reuse safe. Rowsum via ones-column MFMA (truncation bias in
// P cancels in the P/rowsum ratio). LDS 57 KB -> 2 blocks/CU (grid caps it).
// ---------------------------------------------------------------------------
__global__ __launch_bounds__(256) void attn_mfma_kernel(
    const ushort* __restrict__ Q, const ushort* __restrict__ Kb,
    const ushort* __restrict__ Vt, ushort* __restrict__ Oo) {
  __shared__ ushort Ks[128][64];    // [kv][dk], 8x16B blocks, XOR-swizzled
  __shared__ ushort Vs[128][128];   // [dv][kv], 16x16B blocks, XOR-swizzled
  __shared__ ushort Ps[4][32][36];  // per-wave [q][kv32 + pad]

  const int t = threadIdx.x;
  const int qt = blockIdx.x, h = blockIdx.y, b = blockIdx.z;
  const int w = t >> 6, lane = t & 63;
  const int lr = lane & 15, quad = lane >> 4;
  const int q0 = qt * 128 + w * 32;

  union { bf16x8 v; ushort u[8]; } one8;
#pragma unroll
  for (int i = 0; i < 8; ++i) one8.u[i] = 0x3F80;  // bf16 1.0

  bf16x8 aq[2][2];
#pragma unroll
  for (int mt = 0; mt < 2; ++mt)
#pragma unroll
    for (int kh = 0; kh < 2; ++kh)
      aq[mt][kh] = *(const bf16x8*)&Q[(size_t)(b * SQL + q0 + mt * 16 + lr) *
                                          (NH * DK) +
                                      h * DK + kh * 32 + quad * 8];

  f32x4 accO[2][9];
#pragma unroll
  for (int mt = 0; mt < 2; ++mt)
#pragma unroll
    for (int dn = 0; dn < 9; ++dn) accO[mt][dn] = (f32x4){0.f, 0.f, 0.f, 0.f};

  const ushort* kbase = Kb + (size_t)b * SKV * (NH * DK) + h * DK;
  const ushort* vbase = Vt + (size_t)(b * NH + h) * DV * SKV;

  // K staging: 4 rounds x 32 rows; row = t>>3 (+32rd), phys blk = t&7,
  // logical = phys ^ (row&7)  (row&7 invariant across rounds)
  const int krow = t >> 3;
  const int kblk = (t & 7) ^ (krow & 7);
  const ushort* gK = kbase + (size_t)krow * (NH * DK) + kblk * 8;
  ushort* dK = (ushort*)Ks + t * 8;
  // V staging: 8 rounds x 16 rows; row = t>>4 (+16rd), phys blk = t&15,
  // logical = phys ^ (row&15)
  const int vrow = t >> 4;
  const int vkv = ((t & 15) ^ (vrow & 15)) * 8;
  const ushort* gV = vbase + (size_t)vrow * SKV + vkv;
  ushort* dV = (ushort*)Vs + t * 8;

  const int swk = lr & 7;

  for (int kv0 = 0; kv0 < SKV; kv0 += 128) {
    __syncthreads();
#pragma unroll
    for (int rd = 0; rd < 4; ++rd)
      GLDS16(gK + (size_t)(kv0 + rd * 32) * (NH * DK), dK + rd * 2048);
#pragma unroll
    for (int rd = 0; rd < 8; ++rd)
      GLDS16(gV + (size_t)rd * 16 * SKV + kv0, dV + rd * 2048);
    __syncthreads();

#pragma unroll
    for (int c = 0; c < 4; ++c) {
      // ---- S^T tiles for this 32-kv chunk; P = exp2(S); pack to Ps ----
#pragma unroll
      for (int tt = 0; tt < 2; ++tt) {
        const int nt = c * 2 + tt;
        const bf16x8 fk0 = *(const bf16x8*)&Ks[nt * 16 + lr][(quad ^ swk) * 8];
        const bf16x8 fk1 =
            *(const bf16x8*)&Ks[nt * 16 + lr][((4 + quad) ^ swk) * 8];
#pragma unroll
        for (int mt = 0; mt < 2; ++mt) {
          f32x4 s = (f32x4){0.f, 0.f, 0.f, 0.f};
          s = MFMA16(fk0, aq[mt][0], s);
          s = MFMA16(fk1, aq[mt][1], s);
          const unsigned u0 = __float_as_uint(EXP2(s[0]));
          const unsigned u1 = __float_as_uint(EXP2(s[1]));
          const unsigned u2 = __float_as_uint(EXP2(s[2]));
          const unsigned u3 = __float_as_uint(EXP2(s[3]));
          uint2 dd;
          dd.x = __builtin_amdgcn_perm(u1, u0, 0x07060302u);
          dd.y = __builtin_amdgcn_perm(u3, u2, 0x07060302u);
          *(uint2*)&Ps[w][mt * 16 + lr][tt * 16 + quad * 4] = dd;
        }
      }
      // ---- A-frags of P (chunk-local kv = quad*8 + j) ----
      bf16x8 ap[2];
#pragma unroll
      for (int mt = 0; mt < 2; ++mt) {
        union { bf16x8 v; uint2 u[2]; } fr;
        fr.u[0] = *(const uint2*)&Ps[w][mt * 16 + lr][quad * 8];
        fr.u[1] = *(const uint2*)&Ps[w][mt * 16 + lr][quad * 8 + 4];
        ap[mt] = fr.v;
      }
      // ---- O += P @ V for this chunk; rowsum via ones column ----
#pragma unroll
      for (int dn = 0; dn < 8; ++dn) {
        const bf16x8 fv =
            *(const bf16x8*)&Vs[dn * 16 + lr][((c * 4 + quad) ^ lr) * 8];
        accO[0][dn] = MFMA16(ap[0], fv, accO[0][dn]);
        accO[1][dn] = MFMA16(ap[1], fv, accO[1][dn]);
      }
      accO[0][8] = MFMA16(ap[0], one8.v, accO[0][8]);
      accO[1][8] = MFMA16(ap[1], one8.v, accO[1][8]);
    }
  }

  // ---- normalize: row sums already in C-layout at (quad, r) ----
#pragma unroll
  for (int mt = 0; mt < 2; ++mt) {
    float inv[4];
#pragma unroll
    for (int r = 0; r < 4; ++r) inv[r] = 1.f / accO[mt][8][r];
#pragma unroll
    for (int dn = 0; dn < 8; ++dn)
#pragma unroll
      for (int r = 0; r < 4; ++r) {
        const size_t row = (size_t)b * SQL + q0 + mt * 16 + quad * 4 + r;
        Oo[row * D_MODEL + h * DV + dn * 16 + lr] =
            f2bf(accO[mt][dn][r] * inv[r]);
      }
  }
}

// ---------------------------------------------------------------------------
// Workspace (ushorts): encb 8.39M | preb 8.39M | WqT .52M | WkT .52M |
// WvT 1.05M (contig Wqkv) | WoT 1.05M | qb 4.19M | kb 4.19M | vt 8.39M (~73MB)
// Alias: ao = encb (encb's last reader is gemm_qkv; attn writes after).
// vb eliminated: v goes straight to vt in gemm_qkv's epilogue.
// ---------------------------------------------------------------------------
extern "C" void kernel_launch(void* const* d_in, const int* in_sizes, int n_in,
                              void* d_out, int out_size, void* d_ws,
                              size_t ws_size, hipStream_t stream) {
  const float* enc = (const float*)d_in[0];
  const float* pre = (const float*)d_in[1];
  const float* Wq = (const float*)d_in[2];
  const float* Wk = (const float*)d_in[3];
  const float* Wv = (const float*)d_in[4];
  const float* Wo = (const float*)d_in[5];
  float* out = (float*)d_out;

  const int M = BB * SQL;  // 8192

  ushort* encb = (ushort*)d_ws;
  ushort* preb = encb + (size_t)M * D_MODEL;
  ushort* WqT = preb + (size_t)M * D_MODEL;
  ushort* WkT = WqT + (size_t)(NH * DK) * D_MODEL;
  ushort* WvT = WkT + (size_t)(NH * DK) * D_MODEL;
  ushort* WoT = WvT + (size_t)D_MODEL * D_MODEL;
  ushort* qb = WoT + (size_t)D_MODEL * D_MODEL;
  ushort* kb = qb + (size_t)M * (NH * DK);
  ushort* vt = kb + (size_t)M * (NH * DK);
  ushort* ao = encb;  // alias

  const int n4 = M * D_MODEL / 4;
  dim3 blk(256);
  dim3 tblk(32, 8);

  cvt2_kernel<<<dim3(n4 / 256, 1, 2), blk, 0, stream>>>(enc, pre, encb, preb,
                                                        n4);
  cvt_t4_kernel<<<dim3(32, 32, 4), tblk, 0, stream>>>(Wq, Wk, Wv, Wo, WqT, WkT,
                                                      WvT, WoT);

  // fused q+k+v projection (+v transpose); q pre-scaled by log2e/sqrt(dk)
  gemm_qkv_kernel<<<dim3(16, 64), blk, 0, stream>>>(
      preb, encb, WqT, qb, kb, vt, 0.18033688011112042f);

  attn_mfma_kernel<<<dim3(SQL / 128, NH, BB), blk, 0, stream>>>(qb, kb, vt, ao);

  gemm_o_kernel<<<dim3(8, 64), blk, 0, stream>>>(ao, WoT, out);
}

// Round 2
// 264.534 us; speedup vs baseline: 1.0776x; 1.0776x over previous
//
#include <hip/hip_runtime.h>
#include <math.h>

#define D_MODEL 1024
#define DK 64
#define DV 128
#define NH 8
#define BB 4
#define SQL 2048
#define SKV 2048

typedef __bf16 bf16x8 __attribute__((ext_vector_type(8)));
typedef float f32x4 __attribute__((ext_vector_type(4)));

#if __has_builtin(__builtin_amdgcn_exp2f)
#define EXP2(x) __builtin_amdgcn_exp2f(x)
#else
#define EXP2(x) exp2f(x)
#endif

#define MFMA16(a, b, c) __builtin_amdgcn_mfma_f32_16x16x32_bf16(a, b, c, 0, 0, 0)

// fp32 -> bf16 round-to-nearest-even
__device__ __forceinline__ ushort f2bf(float f) {
  unsigned u = __float_as_uint(f);
  u += 0x7FFFu + ((u >> 16) & 1u);
  return (ushort)(u >> 16);
}
// pack two fp32 -> bf16x2 (RNE both halves)
__device__ __forceinline__ unsigned pk2bf(float lo, float hi) {
  unsigned ul = __float_as_uint(lo);
  unsigned uh = __float_as_uint(hi);
  ul += 0x7FFFu + ((ul >> 16) & 1u);
  uh += 0x7FFFu + ((uh >> 16) & 1u);
  return __builtin_amdgcn_perm(uh, ul, 0x07060302u);
}

// async global->LDS, 16B per lane; dest = wave-uniform base + lane*16
#define GLDS16(g, l)                                                       \
  __builtin_amdgcn_global_load_lds(                                        \
      (const __attribute__((address_space(1))) unsigned int*)(g),          \
      (__attribute__((address_space(3))) unsigned int*)(l), 16, 0, 0)

// ---------------------------------------------------------------------------
// fp32 -> bf16 elementwise, two tensors in one dispatch (z selects)
// ---------------------------------------------------------------------------
__global__ __launch_bounds__(256) void cvt2_kernel(
    const float* __restrict__ s0, const float* __restrict__ s1,
    ushort* __restrict__ d0, ushort* __restrict__ d1, int n4) {
  const float* src = blockIdx.z ? s1 : s0;
  ushort* dst = blockIdx.z ? d1 : d0;
  int i = blockIdx.x * 256 + threadIdx.x;
  if (i >= n4) return;
  float4 v = ((const float4*)src)[i];
  ushort4 o;
  o.x = f2bf(v.x); o.y = f2bf(v.y); o.z = f2bf(v.z); o.w = f2bf(v.w);
  ((ushort4*)dst)[i] = o;
}

// ---------------------------------------------------------------------------
// Four weight transposes (fp32 [1024][C] -> bf16 [C][1024]) in one dispatch.
// ---------------------------------------------------------------------------
__global__ __launch_bounds__(256) void cvt_t4_kernel(
    const float* __restrict__ W0, const float* __restrict__ W1,
    const float* __restrict__ W2, const float* __restrict__ W3,
    ushort* __restrict__ T0, ushort* __restrict__ T1, ushort* __restrict__ T2,
    ushort* __restrict__ T3) {
  __shared__ ushort T[32][34];
  const int z = blockIdx.z;
  const int C = (z < 2) ? 512 : 1024;
  const int c0 = blockIdx.y * 32;
  if (c0 >= C) return;
  const float* W = (z == 0) ? W0 : (z == 1) ? W1 : (z == 2) ? W2 : W3;
  ushort* Wt = (z == 0) ? T0 : (z == 1) ? T1 : (z == 2) ? T2 : T3;
  const int R = 1024;
  const int r0 = blockIdx.x * 32;
  const int tx = threadIdx.x, ty = threadIdx.y;
#pragma unroll
  for (int i = 0; i < 4; ++i) {
    const int rr = ty + i * 8;
    T[rr][tx] = f2bf(W[(size_t)(r0 + rr) * C + c0 + tx]);
  }
  __syncthreads();
#pragma unroll
  for (int i = 0; i < 4; ++i) {
    const int rr = ty + i * 8;
    Wt[(size_t)(c0 + rr) * R + r0 + tx] = T[tx][rr];
  }
}

// ---------------------------------------------------------------------------
// GEMM core: acc[4][4] = Atile[128,K] @ Bttile[128,K]^T (per-wave 64x64).
// m97 global_load_lds staging, BK=32, XOR-swizzled LDS (2-way = free).
// ---------------------------------------------------------------------------
__device__ __forceinline__ void gemm_core_acc(ushort (*As)[32],
                                              ushort (*Bs)[32],
                                              const ushort* At,
                                              const ushort* Bt, int K,
                                              f32x4 (&acc)[4][4]) {
  const int t = threadIdx.x;
  const int w = t >> 6, lane = t & 63;
  const int wm = (w >> 1) * 64, wn = (w & 1) * 64;
  const int lr = lane & 15, quad = lane >> 4;

  const int r0 = t >> 2;
  const int lb = (t & 3) ^ ((r0 >> 1) & 3);
  const ushort* gA0 = At + (size_t)r0 * K + lb * 8;
  const ushort* gA1 = At + (size_t)(r0 + 64) * K + lb * 8;
  const ushort* gB0 = Bt + (size_t)r0 * K + lb * 8;
  const ushort* gB1 = Bt + (size_t)(r0 + 64) * K + lb * 8;
  ushort* dA0 = (ushort*)As + t * 8;
  ushort* dA1 = (ushort*)As + t * 8 + 2048;
  ushort* dB0 = (ushort*)Bs + t * 8;
  ushort* dB1 = (ushort*)Bs + t * 8 + 2048;

  const int sw = (quad ^ ((lr >> 1) & 3)) * 8;

#pragma unroll
  for (int i = 0; i < 4; ++i)
#pragma unroll
    for (int j = 0; j < 4; ++j) acc[i][j] = (f32x4){0.f, 0.f, 0.f, 0.f};

  for (int k0 = 0; k0 < K; k0 += 32) {
    __syncthreads();
    GLDS16(gA0 + k0, dA0);
    GLDS16(gA1 + k0, dA1);
    GLDS16(gB0 + k0, dB0);
    GLDS16(gB1 + k0, dB1);
    __syncthreads();
    bf16x8 fa[4], fb[4];
#pragma unroll
    for (int i = 0; i < 4; ++i) fa[i] = *(const bf16x8*)&As[wm + i * 16 + lr][sw];
#pragma unroll
    for (int j = 0; j < 4; ++j) fb[j] = *(const bf16x8*)&Bs[wn + j * 16 + lr][sw];
#pragma unroll
    for (int i = 0; i < 4; ++i)
#pragma unroll
      for (int j = 0; j < 4; ++j) acc[i][j] = MFMA16(fa[i], fb[j], acc[i][j]);
  }
}

// ---------------------------------------------------------------------------
// Fused QKV projection + v-transpose. WqkvT = [2048][1024] (WqT|WkT|WvT).
// grid (16, 64). n-region: q (direct, pre-scaled), k (direct),
// v (epilogue transposes 128skv x 128dv head-tile into vt[bh][dv][skv] via
// per-wave LDS stage; RNE packing — truncation bias would NOT cancel here).
// ---------------------------------------------------------------------------
__global__ __launch_bounds__(256) void gemm_qkv_kernel(
    const ushort* __restrict__ preb, const ushort* __restrict__ encb,
    const ushort* __restrict__ WqkvT, ushort* __restrict__ qb,
    ushort* __restrict__ kb, ushort* __restrict__ vt, float qsc) {
  __shared__ ushort shm[17408];  // union: staging 8192 | v-epilogue 17408
  ushort(*As)[32] = (ushort(*)[32])shm;
  ushort(*Bs)[32] = (ushort(*)[32])(shm + 4096);

  const int n0 = blockIdx.x * 128, m0 = blockIdx.y * 128;
  const int t = threadIdx.x;
  const int w = t >> 6, lane = t & 63;
  const int wm = (w >> 1) * 64, wn = (w & 1) * 64;
  const int lr = lane & 15, quad = lane >> 4;

  const ushort* A = (n0 < 512) ? preb : encb;
  f32x4 acc[4][4];
  gemm_core_acc(As, Bs, A + (size_t)m0 * D_MODEL, WqkvT + (size_t)n0 * D_MODEL,
                D_MODEL, acc);

  if (n0 < 1024) {
    ushort* C = (n0 < 512) ? qb : kb;
    const int ncol = (n0 < 512) ? n0 : n0 - 512;
    const float osc = (n0 < 512) ? qsc : 1.f;
#pragma unroll
    for (int i = 0; i < 4; ++i)
#pragma unroll
      for (int j = 0; j < 4; ++j)
#pragma unroll
        for (int r = 0; r < 4; ++r) {
          const int row = m0 + wm + i * 16 + quad * 4 + r;
          const int col = ncol + wn + j * 16 + lr;
          C[(size_t)row * 512 + col] = f2bf(acc[i][j][r] * osc);
        }
  } else {
    // v-region: tile = head h, batch b; write transposed into vt[bh][dv][skv]
    const int h = (n0 - 1024) >> 7;
    const int b = m0 >> 11;
    const int skv0 = m0 & 2047;
    __syncthreads();  // all waves done reading As/Bs
    ushort(*Ep)[68] = (ushort(*)[68])(shm + w * 4352);  // per-wave [dv64][skv64+4]
#pragma unroll
    for (int i = 0; i < 4; ++i)
#pragma unroll
      for (int j = 0; j < 4; ++j) {
        uint2 dd;
        dd.x = pk2bf(acc[i][j][0], acc[i][j][1]);
        dd.y = pk2bf(acc[i][j][2], acc[i][j][3]);
        *(uint2*)&Ep[j * 16 + lr][i * 16 + quad * 4] = dd;
      }
    // per-wave region: no barrier needed before reading own Ep
    ushort* vbase =
        vt + ((size_t)(b * NH + h) * DV + wn) * SKV + skv0 + wm;
#pragma unroll
    for (int rep = 0; rep < 8; ++rep) {
      const int dvl = (lane >> 3) + rep * 8;
      const int skvc = (lane & 7) * 8;
      *(uint4*)&vbase[(size_t)dvl * SKV + skvc] = *(const uint4*)&Ep[dvl][skvc];
    }
  }
}

// ---------------------------------------------------------------------------
// Output projection: out fp32 [8192][1024] = ao @ WoT^T. grid (8, 64).
// ---------------------------------------------------------------------------
__global__ __launch_bounds__(256) void gemm_o_kernel(
    const ushort* __restrict__ ao, const ushort* __restrict__ WoT,
    float* __restrict__ out) {
  __shared__ ushort As[128][32];
  __shared__ ushort Bs[128][32];
  const int n0 = blockIdx.x * 128, m0 = blockIdx.y * 128;
  const int t = threadIdx.x;
  const int w = t >> 6, lane = t & 63;
  const int wm = (w >> 1) * 64, wn = (w & 1) * 64;
  const int lr = lane & 15, quad = lane >> 4;
  f32x4 acc[4][4];
  gemm_core_acc(As, Bs, ao + (size_t)m0 * D_MODEL, WoT + (size_t)n0 * D_MODEL,
                D_MODEL, acc);
#pragma unroll
  for (int i = 0; i < 4; ++i)
#pragma unroll
    for (int j = 0; j < 4; ++j)
#pragma unroll
      for (int r = 0; r < 4; ++r) {
        const int row = m0 + wm + i * 16 + quad * 4 + r;
        const int col = n0 + wn + j * 16 + lr;
        out[(size_t)row * D_MODEL + col] = acc[i][j][r];
      }
}

// ---------------------------------------------------------------------------
// Attention, S^T formulation. KV-tile = 64, DOUBLE-BUFFERED (T3+T4): prefetch
// tile t+1 while computing tile t; raw s_barrier + counted s_waitcnt vmcnt(6)
// (never 0 in the main loop) so staging latency hides under MFMA. T5 setprio
// around the PV cluster. T1 XCD-swizzle: all 16 q-tiles of a (b,h) land on
// one XCD -> K/V (768KB x 4 resident groups = 3MB) stays in the 4MB L2.
// LDS 58368B (same as single-buffered kv128) -> 2 blocks/CU.
// ---------------------------------------------------------------------------
__global__ __launch_bounds__(256) void attn_mfma_kernel(
    const ushort* __restrict__ Q, const ushort* __restrict__ Kb,
    const ushort* __restrict__ Vt, ushort* __restrict__ Oo) {
  __shared__ ushort Ks[2][64][64];   // [buf][kv][dk], 8x16B blocks, XOR-swz
  __shared__ ushort Vs[2][128][64];  // [buf][dv][kv], 8x16B blocks, XOR-swz
  __shared__ ushort Ps[4][32][36];   // per-wave [q][kv32 + pad]

  const int t = threadIdx.x;
  // XCD-aware bijective remap (nwg=512, 512%8==0): hardware round-robins
  // blocks over 8 XCDs; remap so each XCD gets 64 consecutive logical blocks
  // = 4 full (b,h) groups (16 q-tiles each) -> K/V L2-resident per XCD.
  const int n = blockIdx.x + 16 * blockIdx.y + 128 * blockIdx.z;
  const int l = (n & 7) * 64 + (n >> 3);
  const int qt = l & 15, h = (l >> 4) & 7, b = l >> 7;

  const int w = t >> 6, lane = t & 63;
  const int lr = lane & 15, quad = lane >> 4;
  const int q0 = qt * 128 + w * 32;
  const int swk = lr & 7;

  union { bf16x8 v; ushort u[8]; } one8;
#pragma unroll
  for (int i = 0; i < 8; ++i) one8.u[i] = 0x3F80;  // bf16 1.0

  bf16x8 aq[2][2];
#pragma unroll
  for (int mt = 0; mt < 2; ++mt)
#pragma unroll
    for (int kh = 0; kh < 2; ++kh)
      aq[mt][kh] = *(const bf16x8*)&Q[(size_t)(b * SQL + q0 + mt * 16 + lr) *
                                          (NH * DK) +
                                      h * DK + kh * 32 + quad * 8];

  f32x4 accO[2][9];
#pragma unroll
  for (int mt = 0; mt < 2; ++mt)
#pragma unroll
    for (int dn = 0; dn < 9; ++dn) accO[mt][dn] = (f32x4){0.f, 0.f, 0.f, 0.f};

  const ushort* kbase = Kb + (size_t)b * SKV * (NH * DK) + h * DK;
  const ushort* vbase = Vt + (size_t)(b * NH + h) * DV * SKV;

  // staging: rows of 64 ushorts = 8 x 16B blocks; 256 lanes cover 32 rows
  // per GLDS round. row = t>>3, phys blk = t&7, logical = phys ^ (row&7);
  // row&7 invariant across +32-row rounds.
  const int srow = t >> 3;
  const int sb7 = (t & 7) ^ (srow & 7);
  const ushort* gK = kbase + (size_t)srow * (NH * DK) + sb7 * 8;
  const ushort* gV = vbase + (size_t)srow * SKV + sb7 * 8;
  ushort* dK = (ushort*)Ks + t * 8;
  ushort* dV = (ushort*)Vs + t * 8;

  // K tile 64x64 = 2 rounds; V tile 128x64 = 4 rounds; 6 GLDS per tile.
  auto stage = [&](int kv0, int buf) {
    const ushort* gk = gK + (size_t)kv0 * (NH * DK);
    ushort* dk = dK + buf * 4096;
    GLDS16(gk, dk);
    GLDS16(gk + (size_t)32 * (NH * DK), dk + 2048);
    const ushort* gv = gV + kv0;
    ushort* dv = dV + buf * 8192;
    GLDS16(gv, dv);
    GLDS16(gv + (size_t)32 * SKV, dv + 2048);
    GLDS16(gv + (size_t)64 * SKV, dv + 4096);
    GLDS16(gv + (size_t)96 * SKV, dv + 6144);
  };

  // one 32-kv chunk: S^T -> exp2 -> pack to Ps -> A-frags -> PV (+rowsum)
  auto chunk = [&](const ushort(*Kc)[64], const ushort(*Vc)[64], int c) {
#pragma unroll
    for (int tt = 0; tt < 2; ++tt) {
      const int nt = c * 2 + tt;
      const bf16x8 fk0 = *(const bf16x8*)&Kc[nt * 16 + lr][(quad ^ swk) * 8];
      const bf16x8 fk1 =
          *(const bf16x8*)&Kc[nt * 16 + lr][((4 + quad) ^ swk) * 8];
#pragma unroll
      for (int mt = 0; mt < 2; ++mt) {
        f32x4 s = (f32x4){0.f, 0.f, 0.f, 0.f};
        s = MFMA16(fk0, aq[mt][0], s);
        s = MFMA16(fk1, aq[mt][1], s);
        const unsigned u0 = __float_as_uint(EXP2(s[0]));
        const unsigned u1 = __float_as_uint(EXP2(s[1]));
        const unsigned u2 = __float_as_uint(EXP2(s[2]));
        const unsigned u3 = __float_as_uint(EXP2(s[3]));
        uint2 dd;
        dd.x = __builtin_amdgcn_perm(u1, u0, 0x07060302u);
        dd.y = __builtin_amdgcn_perm(u3, u2, 0x07060302u);
        *(uint2*)&Ps[w][mt * 16 + lr][tt * 16 + quad * 4] = dd;
      }
    }
    bf16x8 ap[2];
#pragma unroll
    for (int mt = 0; mt < 2; ++mt) {
      union { bf16x8 v; uint2 u[2]; } fr;
      fr.u[0] = *(const uint2*)&Ps[w][mt * 16 + lr][quad * 8];
      fr.u[1] = *(const uint2*)&Ps[w][mt * 16 + lr][quad * 8 + 4];
      ap[mt] = fr.v;
    }
    __builtin_amdgcn_s_setprio(1);
#pragma unroll
    for (int dn = 0; dn < 8; ++dn) {
      const bf16x8 fv =
          *(const bf16x8*)&Vc[dn * 16 + lr][((c * 4 + quad) ^ swk) * 8];
      accO[0][dn] = MFMA16(ap[0], fv, accO[0][dn]);
      accO[1][dn] = MFMA16(ap[1], fv, accO[1][dn]);
    }
    accO[0][8] = MFMA16(ap[0], one8.v, accO[0][8]);
    accO[1][8] = MFMA16(ap[1], one8.v, accO[1][8]);
    __builtin_amdgcn_s_setprio(0);
  };

  stage(0, 0);
  for (int ti = 0; ti < 31; ++ti) {
    stage((ti + 1) * 64, (ti + 1) & 1);
    // tile ti's 6 loads retired (in-order); tile ti+1's 6 stay in flight
    asm volatile("s_waitcnt vmcnt(6)" ::: "memory");
    __builtin_amdgcn_s_barrier();
    __builtin_amdgcn_sched_barrier(0);
    const ushort(*Kc)[64] = Ks[ti & 1];
    const ushort(*Vc)[64] = Vs[ti & 1];
    chunk(Kc, Vc, 0);
    chunk(Kc, Vc, 1);
    __builtin_amdgcn_sched_barrier(0);
    __builtin_amdgcn_s_barrier();  // all waves done reading before overwrite
  }
  asm volatile("s_waitcnt vmcnt(0)" ::: "memory");
  __builtin_amdgcn_s_barrier();
  __builtin_amdgcn_sched_barrier(0);
  chunk(Ks[1], Vs[1], 0);
  chunk(Ks[1], Vs[1], 1);

  // ---- normalize: row sums already in C-layout at (quad, r) ----
#pragma unroll
  for (int mt = 0; mt < 2; ++mt) {
    float inv[4];
#pragma unroll
    for (int r = 0; r < 4; ++r) inv[r] = 1.f / accO[mt][8][r];
#pragma unroll
    for (int dn = 0; dn < 8; ++dn)
#pragma unroll
      for (int r = 0; r < 4; ++r) {
        const size_t row = (size_t)b * SQL + q0 + mt * 16 + quad * 4 + r;
        Oo[row * D_MODEL + h * DV + dn * 16 + lr] =
            f2bf(accO[mt][dn][r] * inv[r]);
      }
  }
}

// ---------------------------------------------------------------------------
// Workspace (ushorts): encb 8.39M | preb 8.39M | WqT .52M | WkT .52M |
// WvT 1.05M (contig Wqkv) | WoT 1.05M | qb 4.19M | kb 4.19M | vt 8.39M (~73MB)
// Alias: ao = encb (encb's last reader is gemm_qkv; attn writes after).
// vb eliminated: v goes straight to vt in gemm_qkv's epilogue.
// ---------------------------------------------------------------------------
extern "C" void kernel_launch(void* const* d_in, const int* in_sizes, int n_in,
                              void* d_out, int out_size, void* d_ws,
                              size_t ws_size, hipStream_t stream) {
  const float* enc = (const float*)d_in[0];
  const float* pre = (const float*)d_in[1];
  const float* Wq = (const float*)d_in[2];
  const float* Wk = (const float*)d_in[3];
  const float* Wv = (const float*)d_in[4];
  const float* Wo = (const float*)d_in[5];
  float* out = (float*)d_out;

  const int M = BB * SQL;  // 8192

  ushort* encb = (ushort*)d_ws;
  ushort* preb = encb + (size_t)M * D_MODEL;
  ushort* WqT = preb + (size_t)M * D_MODEL;
  ushort* WkT = WqT + (size_t)(NH * DK) * D_MODEL;
  ushort* WvT = WkT + (size_t)(NH * DK) * D_MODEL;
  ushort* WoT = WvT + (size_t)D_MODEL * D_MODEL;
  ushort* qb = WoT + (size_t)D_MODEL * D_MODEL;
  ushort* kb = qb + (size_t)M * (NH * DK);
  ushort* vt = kb + (size_t)M * (NH * DK);
  ushort* ao = encb;  // alias

  const int n4 = M * D_MODEL / 4;
  dim3 blk(256);
  dim3 tblk(32, 8);

  cvt2_kernel<<<dim3(n4 / 256, 1, 2), blk, 0, stream>>>(enc, pre, encb, preb,
                                                        n4);
  cvt_t4_kernel<<<dim3(32, 32, 4), tblk, 0, stream>>>(Wq, Wk, Wv, Wo, WqT, WkT,
                                                      WvT, WoT);

  // fused q+k+v projection (+v transpose); q pre-scaled by log2e/sqrt(dk)
  gemm_qkv_kernel<<<dim3(16, 64), blk, 0, stream>>>(
      preb, encb, WqT, qb, kb, vt, 0.18033688011112042f);

  attn_mfma_kernel<<<dim3(SQL / 128, NH, BB), blk, 0, stream>>>(qb, kb, vt, ao);

  gemm_o_kernel<<<dim3(8, 64), blk, 0, stream>>>(ao, WoT, out);
}

// Round 5
// 260.118 us; speedup vs baseline: 1.0959x; 1.0170x over previous
//
#include <hip/hip_runtime.h>
#include <math.h>

#define D_MODEL 1024
#define DK 64
#define DV 128
#define NH 8
#define BB 4
#define SQL 2048
#define SKV 2048

typedef __bf16 bf16x8 __attribute__((ext_vector_type(8)));
typedef float f32x4 __attribute__((ext_vector_type(4)));

#if __has_builtin(__builtin_amdgcn_exp2f)
#define EXP2(x) __builtin_amdgcn_exp2f(x)
#else
#define EXP2(x) exp2f(x)
#endif

#define MFMA16(a, b, c) __builtin_amdgcn_mfma_f32_16x16x32_bf16(a, b, c, 0, 0, 0)

// fp32 -> bf16 round-to-nearest-even
__device__ __forceinline__ ushort f2bf(float f) {
  unsigned u = __float_as_uint(f);
  u += 0x7FFFu + ((u >> 16) & 1u);
  return (ushort)(u >> 16);
}
// pack two fp32 -> bf16x2 (RNE both halves)
__device__ __forceinline__ unsigned pk2bf(float lo, float hi) {
  unsigned ul = __float_as_uint(lo);
  unsigned uh = __float_as_uint(hi);
  ul += 0x7FFFu + ((ul >> 16) & 1u);
  uh += 0x7FFFu + ((uh >> 16) & 1u);
  return __builtin_amdgcn_perm(uh, ul, 0x07060302u);
}

// async global->LDS, 16B per lane; dest = wave-uniform base + lane*16
#define GLDS16(g, l)                                                       \
  __builtin_amdgcn_global_load_lds(                                        \
      (const __attribute__((address_space(1))) unsigned int*)(g),          \
      (__attribute__((address_space(3))) unsigned int*)(l), 16, 0, 0)

// ---------------------------------------------------------------------------
// fp32 -> bf16 elementwise, two tensors in one dispatch (z selects)
// ---------------------------------------------------------------------------
__global__ __launch_bounds__(256) void cvt2_kernel(
    const float* __restrict__ s0, const float* __restrict__ s1,
    ushort* __restrict__ d0, ushort* __restrict__ d1, int n4) {
  const float* src = blockIdx.z ? s1 : s0;
  ushort* dst = blockIdx.z ? d1 : d0;
  int i = blockIdx.x * 256 + threadIdx.x;
  if (i >= n4) return;
  float4 v = ((const float4*)src)[i];
  ushort4 o;
  o.x = f2bf(v.x); o.y = f2bf(v.y); o.z = f2bf(v.z); o.w = f2bf(v.w);
  ((ushort4*)dst)[i] = o;
}

// ---------------------------------------------------------------------------
// Four weight transposes (fp32 [1024][C] -> bf16 [C][1024]) in one dispatch.
// ---------------------------------------------------------------------------
__global__ __launch_bounds__(256) void cvt_t4_kernel(
    const float* __restrict__ W0, const float* __restrict__ W1,
    const float* __restrict__ W2, const float* __restrict__ W3,
    ushort* __restrict__ T0, ushort* __restrict__ T1, ushort* __restrict__ T2,
    ushort* __restrict__ T3) {
  __shared__ ushort T[32][34];
  const int z = blockIdx.z;
  const int C = (z < 2) ? 512 : 1024;
  const int c0 = blockIdx.y * 32;
  if (c0 >= C) return;
  const float* W = (z == 0) ? W0 : (z == 1) ? W1 : (z == 2) ? W2 : W3;
  ushort* Wt = (z == 0) ? T0 : (z == 1) ? T1 : (z == 2) ? T2 : T3;
  const int R = 1024;
  const int r0 = blockIdx.x * 32;
  const int tx = threadIdx.x, ty = threadIdx.y;
#pragma unroll
  for (int i = 0; i < 4; ++i) {
    const int rr = ty + i * 8;
    T[rr][tx] = f2bf(W[(size_t)(r0 + rr) * C + c0 + tx]);
  }
  __syncthreads();
#pragma unroll
  for (int i = 0; i < 4; ++i) {
    const int rr = ty + i * 8;
    Wt[(size_t)(c0 + rr) * R + r0 + tx] = T[tx][rr];
  }
}

// ---------------------------------------------------------------------------
// GEMM core: acc[4][4] = Atile[128,K] @ Bttile[128,K]^T (per-wave 64x64).
// 2-phase dbuf pipeline, race-free by construction: stage(next buf) is issued
// EARLY (before the 16-MFMA compute on the current buf), and the iteration
// ends with a plain __syncthreads() (full vmcnt/lgkmcnt drain + barrier), so
// the prefetch latency hides under compute and every buffer swap is fenced by
// compiler-guaranteed barrier semantics. One barrier per K-step (was 2).
// LDS layout: A0|A1half|B0|B0half | A1|B1 = 2 x 8192 ushorts. XOR-swizzled.
// ---------------------------------------------------------------------------
__device__ __forceinline__ void gemm_core_acc(ushort* sh, const ushort* At,
                                              const ushort* Bt, int K,
                                              f32x4 (&acc)[4][4]) {
  const int t = threadIdx.x;
  const int w = t >> 6, lane = t & 63;
  const int wm = (w >> 1) * 64, wn = (w & 1) * 64;
  const int lr = lane & 15, quad = lane >> 4;

  const int r0 = t >> 2;
  const int lb = (t & 3) ^ ((r0 >> 1) & 3);
  const ushort* gA0 = At + (size_t)r0 * K + lb * 8;
  const ushort* gA1 = At + (size_t)(r0 + 64) * K + lb * 8;
  const ushort* gB0 = Bt + (size_t)r0 * K + lb * 8;
  const ushort* gB1 = Bt + (size_t)(r0 + 64) * K + lb * 8;

  const int sw = (quad ^ ((lr >> 1) & 3)) * 8;

#pragma unroll
  for (int i = 0; i < 4; ++i)
#pragma unroll
    for (int j = 0; j < 4; ++j) acc[i][j] = (f32x4){0.f, 0.f, 0.f, 0.f};

  auto stage = [&](int k0, int buf) {
    ushort* d = sh + buf * 8192 + t * 8;
    GLDS16(gA0 + k0, d);
    GLDS16(gA1 + k0, d + 2048);
    GLDS16(gB0 + k0, d + 4096);
    GLDS16(gB1 + k0, d + 6144);
  };

  stage(0, 0);
  __syncthreads();

  for (int k0 = 0; k0 < K; k0 += 32) {
    const int cur = (k0 >> 5) & 1;
    const bool more = (k0 + 32 < K);
    if (more) stage(k0 + 32, cur ^ 1);  // issue-early: hides under MFMA below
    const ushort(*A)[32] = (const ushort(*)[32])(sh + cur * 8192);
    const ushort(*B)[32] = (const ushort(*)[32])(sh + cur * 8192 + 4096);
    bf16x8 fa[4], fb[4];
#pragma unroll
    for (int i = 0; i < 4; ++i) fa[i] = *(const bf16x8*)&A[wm + i * 16 + lr][sw];
#pragma unroll
    for (int j = 0; j < 4; ++j) fb[j] = *(const bf16x8*)&B[wn + j * 16 + lr][sw];
#pragma unroll
    for (int i = 0; i < 4; ++i)
#pragma unroll
      for (int j = 0; j < 4; ++j) acc[i][j] = MFMA16(fa[i], fb[j], acc[i][j]);
    if (more) __syncthreads();  // drains prefetch + fences buffer swap
  }
}

// ---------------------------------------------------------------------------
// Fused QKV projection + v-transpose. WqkvT = [2048][1024] (WqT|WkT|WvT).
// grid (16, 64). n-region: q (direct, pre-scaled), k (direct),
// v (epilogue transposes 128skv x 128dv head-tile into vt[bh][dv][skv] via
// per-wave LDS stage; RNE packing — truncation bias would NOT cancel here).
// shm union: dbuf staging 32KB | v-epilogue 34.8KB.
// ---------------------------------------------------------------------------
__global__ __launch_bounds__(256) void gemm_qkv_kernel(
    const ushort* __restrict__ preb, const ushort* __restrict__ encb,
    const ushort* __restrict__ WqkvT, ushort* __restrict__ qb,
    ushort* __restrict__ kb, ushort* __restrict__ vt, float qsc) {
  __shared__ __attribute__((aligned(16))) ushort shm[17408];

  const int n0 = blockIdx.x * 128, m0 = blockIdx.y * 128;
  const int t = threadIdx.x;
  const int w = t >> 6, lane = t & 63;
  const int wm = (w >> 1) * 64, wn = (w & 1) * 64;
  const int lr = lane & 15, quad = lane >> 4;

  const ushort* A = (n0 < 512) ? preb : encb;
  f32x4 acc[4][4];
  gemm_core_acc(shm, A + (size_t)m0 * D_MODEL, WqkvT + (size_t)n0 * D_MODEL,
                D_MODEL, acc);

  if (n0 < 1024) {
    ushort* C = (n0 < 512) ? qb : kb;
    const int ncol = (n0 < 512) ? n0 : n0 - 512;
    const float osc = (n0 < 512) ? qsc : 1.f;
#pragma unroll
    for (int i = 0; i < 4; ++i)
#pragma unroll
      for (int j = 0; j < 4; ++j)
#pragma unroll
        for (int r = 0; r < 4; ++r) {
          const int row = m0 + wm + i * 16 + quad * 4 + r;
          const int col = ncol + wn + j * 16 + lr;
          C[(size_t)row * 512 + col] = f2bf(acc[i][j][r] * osc);
        }
  } else {
    // v-region: tile = head h, batch b; write transposed into vt[bh][dv][skv]
    const int h = (n0 - 1024) >> 7;
    const int b = m0 >> 11;
    const int skv0 = m0 & 2047;
    __syncthreads();  // all waves done with staging LDS
    ushort(*Ep)[68] = (ushort(*)[68])(shm + w * 4352);  // per-wave [dv64][skv64+4]
#pragma unroll
    for (int i = 0; i < 4; ++i)
#pragma unroll
      for (int j = 0; j < 4; ++j) {
        uint2 dd;
        dd.x = pk2bf(acc[i][j][0], acc[i][j][1]);
        dd.y = pk2bf(acc[i][j][2], acc[i][j][3]);
        *(uint2*)&Ep[j * 16 + lr][i * 16 + quad * 4] = dd;
      }
    // per-wave region: no barrier needed before reading own Ep
    ushort* vbase =
        vt + ((size_t)(b * NH + h) * DV + wn) * SKV + skv0 + wm;
#pragma unroll
    for (int rep = 0; rep < 8; ++rep) {
      const int dvl = (lane >> 3) + rep * 8;
      const int skvc = (lane & 7) * 8;
      *(uint4*)&vbase[(size_t)dvl * SKV + skvc] = *(const uint4*)&Ep[dvl][skvc];
    }
  }
}

// ---------------------------------------------------------------------------
// Output projection: out fp32 [8192][1024] = ao @ WoT^T. grid (8, 64).
// ---------------------------------------------------------------------------
__global__ __launch_bounds__(256) void gemm_o_kernel(
    const ushort* __restrict__ ao, const ushort* __restrict__ WoT,
    float* __restrict__ out) {
  __shared__ __attribute__((aligned(16))) ushort sh[16384];
  const int n0 = blockIdx.x * 128, m0 = blockIdx.y * 128;
  const int t = threadIdx.x;
  const int w = t >> 6, lane = t & 63;
  const int wm = (w >> 1) * 64, wn = (w & 1) * 64;
  const int lr = lane & 15, quad = lane >> 4;
  f32x4 acc[4][4];
  gemm_core_acc(sh, ao + (size_t)m0 * D_MODEL, WoT + (size_t)n0 * D_MODEL,
                D_MODEL, acc);
#pragma unroll
  for (int i = 0; i < 4; ++i)
#pragma unroll
    for (int j = 0; j < 4; ++j)
#pragma unroll
      for (int r = 0; r < 4; ++r) {
        const int row = m0 + wm + i * 16 + quad * 4 + r;
        const int col = n0 + wn + j * 16 + lr;
        out[(size_t)row * D_MODEL + col] = acc[i][j][r];
      }
}

// ---------------------------------------------------------------------------
// Attention, S^T formulation. KV-tile = 64, DOUBLE-BUFFERED (T3+T4): prefetch
// tile t+1 while computing tile t; raw s_barrier + counted s_waitcnt vmcnt(6)
// (never 0 in the main loop) so staging latency hides under MFMA. T5 setprio
// around the PV cluster. T1 XCD-swizzle: all 16 q-tiles of a (b,h) land on
// one XCD -> K/V (768KB x 4 resident groups = 3MB) stays in the 4MB L2.
// Serial chunk structure: every Ps read is MFMA-consumed before the next Ps
// write (no outstanding-read WAR). VERIFIED at 264.5us total / 76us attn.
// ---------------------------------------------------------------------------
__global__ __launch_bounds__(256) void attn_mfma_kernel(
    const ushort* __restrict__ Q, const ushort* __restrict__ Kb,
    const ushort* __restrict__ Vt, ushort* __restrict__ Oo) {
  __shared__ ushort Ks[2][64][64];   // [buf][kv][dk], 8x16B blocks, XOR-swz
  __shared__ ushort Vs[2][128][64];  // [buf][dv][kv], 8x16B blocks, XOR-swz
  __shared__ ushort Ps[4][32][36];   // per-wave [q][kv32 + pad]

  const int t = threadIdx.x;
  // XCD-aware bijective remap (nwg=512, 512%8==0): each XCD gets 4 full
  // (b,h) groups (16 q-tiles each) -> K/V L2-resident per XCD.
  const int n = blockIdx.x + 16 * blockIdx.y + 128 * blockIdx.z;
  const int l = (n & 7) * 64 + (n >> 3);
  const int qt = l & 15, h = (l >> 4) & 7, b = l >> 7;

  const int w = t >> 6, lane = t & 63;
  const int lr = lane & 15, quad = lane >> 4;
  const int q0 = qt * 128 + w * 32;
  const int swk = lr & 7;

  union { bf16x8 v; ushort u[8]; } one8;
#pragma unroll
  for (int i = 0; i < 8; ++i) one8.u[i] = 0x3F80;  // bf16 1.0

  bf16x8 aq[2][2];
#pragma unroll
  for (int mt = 0; mt < 2; ++mt)
#pragma unroll
    for (int kh = 0; kh < 2; ++kh)
      aq[mt][kh] = *(const bf16x8*)&Q[(size_t)(b * SQL + q0 + mt * 16 + lr) *
                                          (NH * DK) +
                                      h * DK + kh * 32 + quad * 8];

  f32x4 accO[2][9];
#pragma unroll
  for (int mt = 0; mt < 2; ++mt)
#pragma unroll
    for (int dn = 0; dn < 9; ++dn) accO[mt][dn] = (f32x4){0.f, 0.f, 0.f, 0.f};

  const ushort* kbase = Kb + (size_t)b * SKV * (NH * DK) + h * DK;
  const ushort* vbase = Vt + (size_t)(b * NH + h) * DV * SKV;

  // staging: rows of 64 ushorts = 8 x 16B blocks; 256 lanes cover 32 rows
  // per GLDS round. row = t>>3, phys blk = t&7, logical = phys ^ (row&7);
  // row&7 invariant across +32-row rounds.
  const int srow = t >> 3;
  const int sb7 = (t & 7) ^ (srow & 7);
  const ushort* gK = kbase + (size_t)srow * (NH * DK) + sb7 * 8;
  const ushort* gV = vbase + (size_t)srow * SKV + sb7 * 8;
  ushort* dK = (ushort*)Ks + t * 8;
  ushort* dV = (ushort*)Vs + t * 8;

  // K tile 64x64 = 2 rounds; V tile 128x64 = 4 rounds; 6 GLDS per tile.
  auto stage = [&](int kv0, int buf) {
    const ushort* gk = gK + (size_t)kv0 * (NH * DK);
    ushort* dk = dK + buf * 4096;
    GLDS16(gk, dk);
    GLDS16(gk + (size_t)32 * (NH * DK), dk + 2048);
    const ushort* gv = gV + kv0;
    ushort* dv = dV + buf * 8192;
    GLDS16(gv, dv);
    GLDS16(gv + (size_t)32 * SKV, dv + 2048);
    GLDS16(gv + (size_t)64 * SKV, dv + 4096);
    GLDS16(gv + (size_t)96 * SKV, dv + 6144);
  };

  // one 32-kv chunk: S^T -> exp2 -> pack to Ps -> A-frags -> PV (+rowsum)
  auto chunk = [&](const ushort(*Kc)[64], const ushort(*Vc)[64], int c) {
#pragma unroll
    for (int tt = 0; tt < 2; ++tt) {
      const int nt = c * 2 + tt;
      const bf16x8 fk0 = *(const bf16x8*)&Kc[nt * 16 + lr][(quad ^ swk) * 8];
      const bf16x8 fk1 =
          *(const bf16x8*)&Kc[nt * 16 + lr][((4 + quad) ^ swk) * 8];
#pragma unroll
      for (int mt = 0; mt < 2; ++mt) {
        f32x4 s = (f32x4){0.f, 0.f, 0.f, 0.f};
        s = MFMA16(fk0, aq[mt][0], s);
        s = MFMA16(fk1, aq[mt][1], s);
        const unsigned u0 = __float_as_uint(EXP2(s[0]));
        const unsigned u1 = __float_as_uint(EXP2(s[1]));
        const unsigned u2 = __float_as_uint(EXP2(s[2]));
        const unsigned u3 = __float_as_uint(EXP2(s[3]));
        uint2 dd;
        dd.x = __builtin_amdgcn_perm(u1, u0, 0x07060302u);
        dd.y = __builtin_amdgcn_perm(u3, u2, 0x07060302u);
        *(uint2*)&Ps[w][mt * 16 + lr][tt * 16 + quad * 4] = dd;
      }
    }
    bf16x8 ap[2];
#pragma unroll
    for (int mt = 0; mt < 2; ++mt) {
      union { bf16x8 v; uint2 u[2]; } fr;
      fr.u[0] = *(const uint2*)&Ps[w][mt * 16 + lr][quad * 8];
      fr.u[1] = *(const uint2*)&Ps[w][mt * 16 + lr][quad * 8 + 4];
      ap[mt] = fr.v;
    }
    __builtin_amdgcn_s_setprio(1);
#pragma unroll
    for (int dn = 0; dn < 8; ++dn) {
      const bf16x8 fv =
          *(const bf16x8*)&Vc[dn * 16 + lr][((c * 4 + quad) ^ swk) * 8];
      accO[0][dn] = MFMA16(ap[0], fv, accO[0][dn]);
      accO[1][dn] = MFMA16(ap[1], fv, accO[1][dn]);
    }
    accO[0][8] = MFMA16(ap[0], one8.v, accO[0][8]);
    accO[1][8] = MFMA16(ap[1], one8.v, accO[1][8]);
    __builtin_amdgcn_s_setprio(0);
  };

  stage(0, 0);
  for (int ti = 0; ti < 31; ++ti) {
    stage((ti + 1) * 64, (ti + 1) & 1);
    // tile ti's 6 loads retired (in-order); tile ti+1's 6 stay in flight
    asm volatile("s_waitcnt vmcnt(6)" ::: "memory");
    __builtin_amdgcn_s_barrier();
    __builtin_amdgcn_sched_barrier(0);
    const ushort(*Kc)[64] = Ks[ti & 1];
    const ushort(*Vc)[64] = Vs[ti & 1];
    chunk(Kc, Vc, 0);
    chunk(Kc, Vc, 1);
    __builtin_amdgcn_sched_barrier(0);
    __builtin_amdgcn_s_barrier();  // all waves done reading before overwrite
  }
  asm volatile("s_waitcnt vmcnt(0)" ::: "memory");
  __builtin_amdgcn_s_barrier();
  __builtin_amdgcn_sched_barrier(0);
  chunk(Ks[1], Vs[1], 0);
  chunk(Ks[1], Vs[1], 1);

  // ---- normalize: row sums already in C-layout at (quad, r) ----
#pragma unroll
  for (int mt = 0; mt < 2; ++mt) {
    float inv[4];
#pragma unroll
    for (int r = 0; r < 4; ++r) inv[r] = 1.f / accO[mt][8][r];
#pragma unroll
    for (int dn = 0; dn < 8; ++dn)
#pragma unroll
      for (int r = 0; r < 4; ++r) {
        const size_t row = (size_t)b * SQL + q0 + mt * 16 + quad * 4 + r;
        Oo[row * D_MODEL + h * DV + dn * 16 + lr] =
            f2bf(accO[mt][dn][r] * inv[r]);
      }
  }
}

// ---------------------------------------------------------------------------
// Workspace (ushorts): encb 8.39M | preb 8.39M | WqT .52M | WkT .52M |
// WvT 1.05M (contig Wqkv) | WoT 1.05M | qb 4.19M | kb 4.19M | vt 8.39M (~73MB)
// Alias: ao = encb (encb's last reader is gemm_qkv; attn writes after).
// ---------------------------------------------------------------------------
extern "C" void kernel_launch(void* const* d_in, const int* in_sizes, int n_in,
                              void* d_out, int out_size, void* d_ws,
                              size_t ws_size, hipStream_t stream) {
  const float* enc = (const float*)d_in[0];
  const float* pre = (const float*)d_in[1];
  const float* Wq = (const float*)d_in[2];
  const float* Wk = (const float*)d_in[3];
  const float* Wv = (const float*)d_in[4];
  const float* Wo = (const float*)d_in[5];
  float* out = (float*)d_out;

  const int M = BB * SQL;  // 8192

  ushort* encb = (ushort*)d_ws;
  ushort* preb = encb + (size_t)M * D_MODEL;
  ushort* WqT = preb + (size_t)M * D_MODEL;
  ushort* WkT = WqT + (size_t)(NH * DK) * D_MODEL;
  ushort* WvT = WkT + (size_t)(NH * DK) * D_MODEL;
  ushort* WoT = WvT + (size_t)D_MODEL * D_MODEL;
  ushort* qb = WoT + (size_t)D_MODEL * D_MODEL;
  ushort* kb = qb + (size_t)M * (NH * DK);
  ushort* vt = kb + (size_t)M * (NH * DK);
  ushort* ao = encb;  // alias

  const int n4 = M * D_MODEL / 4;
  dim3 blk(256);
  dim3 tblk(32, 8);

  cvt2_kernel<<<dim3(n4 / 256, 1, 2), blk, 0, stream>>>(enc, pre, encb, preb,
                                                        n4);
  cvt_t4_kernel<<<dim3(32, 32, 4), tblk, 0, stream>>>(Wq, Wk, Wv, Wo, WqT, WkT,
                                                      WvT, WoT);

  // fused q+k+v projection (+v transpose); q pre-scaled by log2e/sqrt(dk)
  gemm_qkv_kernel<<<dim3(16, 64), blk, 0, stream>>>(
      preb, encb, WqT, qb, kb, vt, 0.18033688011112042f);

  attn_mfma_kernel<<<dim3(SQL / 128, NH, BB), blk, 0, stream>>>(qb, kb, vt, ao);

  gemm_o_kernel<<<dim3(8, 64), blk, 0, stream>>>(ao, WoT, out);
}

// Round 6
// 253.807 us; speedup vs baseline: 1.1231x; 1.0249x over previous
//
#include <hip/hip_runtime.h>
#include <math.h>

#define D_MODEL 1024
#define DK 64
#define DV 128
#define NH 8
#define BB 4
#define SQL 2048
#define SKV 2048

typedef __bf16 bf16x8 __attribute__((ext_vector_type(8)));
typedef float f32x4 __attribute__((ext_vector_type(4)));

#if __has_builtin(__builtin_amdgcn_exp2f)
#define EXP2(x) __builtin_amdgcn_exp2f(x)
#else
#define EXP2(x) exp2f(x)
#endif

#define MFMA16(a, b, c) __builtin_amdgcn_mfma_f32_16x16x32_bf16(a, b, c, 0, 0, 0)

// fp32 -> bf16 round-to-nearest-even
__device__ __forceinline__ ushort f2bf(float f) {
  unsigned u = __float_as_uint(f);
  u += 0x7FFFu + ((u >> 16) & 1u);
  return (ushort)(u >> 16);
}
// pack two fp32 -> bf16x2 (RNE both halves)
__device__ __forceinline__ unsigned pk2bf(float lo, float hi) {
  unsigned ul = __float_as_uint(lo);
  unsigned uh = __float_as_uint(hi);
  ul += 0x7FFFu + ((ul >> 16) & 1u);
  uh += 0x7FFFu + ((uh >> 16) & 1u);
  return __builtin_amdgcn_perm(uh, ul, 0x07060302u);
}

// async global->LDS, 16B per lane; dest = wave-uniform base + lane*16
#define GLDS16(g, l)                                                       \
  __builtin_amdgcn_global_load_lds(                                        \
      (const __attribute__((address_space(1))) unsigned int*)(g),          \
      (__attribute__((address_space(3))) unsigned int*)(l), 16, 0, 0)

// ---------------------------------------------------------------------------
// fp32 -> bf16 elementwise, two tensors in one dispatch (z selects)
// ---------------------------------------------------------------------------
__global__ __launch_bounds__(256) void cvt2_kernel(
    const float* __restrict__ s0, const float* __restrict__ s1,
    ushort* __restrict__ d0, ushort* __restrict__ d1, int n4) {
  const float* src = blockIdx.z ? s1 : s0;
  ushort* dst = blockIdx.z ? d1 : d0;
  int i = blockIdx.x * 256 + threadIdx.x;
  if (i >= n4) return;
  float4 v = ((const float4*)src)[i];
  ushort4 o;
  o.x = f2bf(v.x); o.y = f2bf(v.y); o.z = f2bf(v.z); o.w = f2bf(v.w);
  ((ushort4*)dst)[i] = o;
}

// ---------------------------------------------------------------------------
// Four weight transposes (fp32 [1024][C] -> bf16 [C][1024]) in one dispatch.
// ---------------------------------------------------------------------------
__global__ __launch_bounds__(256) void cvt_t4_kernel(
    const float* __restrict__ W0, const float* __restrict__ W1,
    const float* __restrict__ W2, const float* __restrict__ W3,
    ushort* __restrict__ T0, ushort* __restrict__ T1, ushort* __restrict__ T2,
    ushort* __restrict__ T3) {
  __shared__ ushort T[32][34];
  const int z = blockIdx.z;
  const int C = (z < 2) ? 512 : 1024;
  const int c0 = blockIdx.y * 32;
  if (c0 >= C) return;
  const float* W = (z == 0) ? W0 : (z == 1) ? W1 : (z == 2) ? W2 : W3;
  ushort* Wt = (z == 0) ? T0 : (z == 1) ? T1 : (z == 2) ? T2 : T3;
  const int R = 1024;
  const int r0 = blockIdx.x * 32;
  const int tx = threadIdx.x, ty = threadIdx.y;
#pragma unroll
  for (int i = 0; i < 4; ++i) {
    const int rr = ty + i * 8;
    T[rr][tx] = f2bf(W[(size_t)(r0 + rr) * C + c0 + tx]);
  }
  __syncthreads();
#pragma unroll
  for (int i = 0; i < 4; ++i) {
    const int rr = ty + i * 8;
    Wt[(size_t)(c0 + rr) * R + r0 + tx] = T[tx][rr];
  }
}

// ---------------------------------------------------------------------------
// GEMM core: acc[4][4] = Atile[128,K] @ Bttile[128,K]^T (per-wave 64x64).
// T4 counted-vmcnt dbuf pipeline, byte-mirroring the verified attn loop:
// stage(next buf) -> s_waitcnt vmcnt(4) (next tile's 4 loads STAY IN FLIGHT
// across the barrier and the whole compute phase) -> s_barrier -> compute ->
// end s_barrier (fences buf^1 overwrite next iteration). Never drains to 0
// in the main loop, so HBM latency hides under a full K-step + 2 barriers.
// ---------------------------------------------------------------------------
__device__ __forceinline__ void gemm_core_acc(ushort* sh, const ushort* At,
                                              const ushort* Bt, int K,
                                              f32x4 (&acc)[4][4]) {
  const int t = threadIdx.x;
  const int w = t >> 6, lane = t & 63;
  const int wm = (w >> 1) * 64, wn = (w & 1) * 64;
  const int lr = lane & 15, quad = lane >> 4;

  const int r0 = t >> 2;
  const int lb = (t & 3) ^ ((r0 >> 1) & 3);
  const ushort* gA0 = At + (size_t)r0 * K + lb * 8;
  const ushort* gA1 = At + (size_t)(r0 + 64) * K + lb * 8;
  const ushort* gB0 = Bt + (size_t)r0 * K + lb * 8;
  const ushort* gB1 = Bt + (size_t)(r0 + 64) * K + lb * 8;

  const int sw = (quad ^ ((lr >> 1) & 3)) * 8;

#pragma unroll
  for (int i = 0; i < 4; ++i)
#pragma unroll
    for (int j = 0; j < 4; ++j) acc[i][j] = (f32x4){0.f, 0.f, 0.f, 0.f};

  auto stage = [&](int k0, int buf) {
    ushort* d = sh + buf * 8192 + t * 8;
    GLDS16(gA0 + k0, d);
    GLDS16(gA1 + k0, d + 2048);
    GLDS16(gB0 + k0, d + 4096);
    GLDS16(gB1 + k0, d + 6144);
  };

  const int NT = K >> 5;  // K-steps of 32
  stage(0, 0);
  for (int ti = 0; ti < NT; ++ti) {
    const bool more = (ti + 1 < NT);
    if (more) {
      stage((ti + 1) * 32, (ti + 1) & 1);
      // cur tile's 4 loads retired (in-order); next tile's 4 stay in flight
      asm volatile("s_waitcnt vmcnt(4)" ::: "memory");
    } else {
      asm volatile("s_waitcnt vmcnt(0)" ::: "memory");
    }
    __builtin_amdgcn_s_barrier();
    __builtin_amdgcn_sched_barrier(0);
    const ushort(*A)[32] = (const ushort(*)[32])(sh + (ti & 1) * 8192);
    const ushort(*B)[32] = (const ushort(*)[32])(sh + (ti & 1) * 8192 + 4096);
    bf16x8 fa[4], fb[4];
#pragma unroll
    for (int i = 0; i < 4; ++i) fa[i] = *(const bf16x8*)&A[wm + i * 16 + lr][sw];
#pragma unroll
    for (int j = 0; j < 4; ++j) fb[j] = *(const bf16x8*)&B[wn + j * 16 + lr][sw];
#pragma unroll
    for (int i = 0; i < 4; ++i)
#pragma unroll
      for (int j = 0; j < 4; ++j) acc[i][j] = MFMA16(fa[i], fb[j], acc[i][j]);
    __builtin_amdgcn_sched_barrier(0);
    if (more) __builtin_amdgcn_s_barrier();  // readers done before overwrite
  }
}

// ---------------------------------------------------------------------------
// Fused QKV projection + v-transpose. WqkvT = [2048][1024] (WqT|WkT|WvT).
// grid (16, 64), T1 XCD-swizzled: each XCD owns 8 contiguous m-panels x all
// 16 n-tiles -> A-panels (2MB/XCD) fetched once and L2-resident (was ~8x).
// n-region: q (direct, pre-scaled), k (direct), v (epilogue transposes
// 128skv x 128dv head-tile into vt[bh][dv][skv] via per-wave LDS stage).
// shm union: dbuf staging 32KB | v-epilogue 34.8KB.
// ---------------------------------------------------------------------------
__global__ __launch_bounds__(256) void gemm_qkv_kernel(
    const ushort* __restrict__ preb, const ushort* __restrict__ encb,
    const ushort* __restrict__ WqkvT, ushort* __restrict__ qb,
    ushort* __restrict__ kb, ushort* __restrict__ vt, float qsc) {
  __shared__ __attribute__((aligned(16))) ushort shm[17408];

  // bijective XCD remap (nwg=1024, %8==0): XCD k gets l in [128k,128(k+1))
  const int nlin = blockIdx.x + 16 * blockIdx.y;
  const int l = (nlin & 7) * 128 + (nlin >> 3);
  const int n0 = (l & 15) * 128, m0 = (l >> 4) * 128;

  const int t = threadIdx.x;
  const int w = t >> 6, lane = t & 63;
  const int wm = (w >> 1) * 64, wn = (w & 1) * 64;
  const int lr = lane & 15, quad = lane >> 4;

  const ushort* A = (n0 < 512) ? preb : encb;
  f32x4 acc[4][4];
  gemm_core_acc(shm, A + (size_t)m0 * D_MODEL, WqkvT + (size_t)n0 * D_MODEL,
                D_MODEL, acc);

  if (n0 < 1024) {
    ushort* C = (n0 < 512) ? qb : kb;
    const int ncol = (n0 < 512) ? n0 : n0 - 512;
    const float osc = (n0 < 512) ? qsc : 1.f;
#pragma unroll
    for (int i = 0; i < 4; ++i)
#pragma unroll
      for (int j = 0; j < 4; ++j)
#pragma unroll
        for (int r = 0; r < 4; ++r) {
          const int row = m0 + wm + i * 16 + quad * 4 + r;
          const int col = ncol + wn + j * 16 + lr;
          C[(size_t)row * 512 + col] = f2bf(acc[i][j][r] * osc);
        }
  } else {
    // v-region: tile = head h, batch b; write transposed into vt[bh][dv][skv]
    const int h = (n0 - 1024) >> 7;
    const int b = m0 >> 11;
    const int skv0 = m0 & 2047;
    __syncthreads();  // all waves done with staging LDS
    ushort(*Ep)[68] = (ushort(*)[68])(shm + w * 4352);  // per-wave [dv64][skv64+4]
#pragma unroll
    for (int i = 0; i < 4; ++i)
#pragma unroll
      for (int j = 0; j < 4; ++j) {
        uint2 dd;
        dd.x = pk2bf(acc[i][j][0], acc[i][j][1]);
        dd.y = pk2bf(acc[i][j][2], acc[i][j][3]);
        *(uint2*)&Ep[j * 16 + lr][i * 16 + quad * 4] = dd;
      }
    // per-wave region: no barrier needed before reading own Ep
    ushort* vbase =
        vt + ((size_t)(b * NH + h) * DV + wn) * SKV + skv0 + wm;
#pragma unroll
    for (int rep = 0; rep < 8; ++rep) {
      const int dvl = (lane >> 3) + rep * 8;
      const int skvc = (lane & 7) * 8;
      *(uint4*)&vbase[(size_t)dvl * SKV + skvc] = *(const uint4*)&Ep[dvl][skvc];
    }
  }
}

// ---------------------------------------------------------------------------
// Output projection: out fp32 [8192][1024] = ao @ WoT^T. grid (8, 64),
// T1 XCD-swizzled (nwg=512, %8==0): XCD k owns m-panels 8k..8k+7 -> ao
// panels (2MB/XCD) + WoT (2MB) both L2-resident.
// ---------------------------------------------------------------------------
__global__ __launch_bounds__(256) void gemm_o_kernel(
    const ushort* __restrict__ ao, const ushort* __restrict__ WoT,
    float* __restrict__ out) {
  __shared__ __attribute__((aligned(16))) ushort sh[16384];
  const int nlin = blockIdx.x + 8 * blockIdx.y;
  const int l = (nlin & 7) * 64 + (nlin >> 3);
  const int n0 = (l & 7) * 128, m0 = (l >> 3) * 128;
  const int t = threadIdx.x;
  const int w = t >> 6, lane = t & 63;
  const int wm = (w >> 1) * 64, wn = (w & 1) * 64;
  const int lr = lane & 15, quad = lane >> 4;
  f32x4 acc[4][4];
  gemm_core_acc(sh, ao + (size_t)m0 * D_MODEL, WoT + (size_t)n0 * D_MODEL,
                D_MODEL, acc);
#pragma unroll
  for (int i = 0; i < 4; ++i)
#pragma unroll
    for (int j = 0; j < 4; ++j)
#pragma unroll
      for (int r = 0; r < 4; ++r) {
        const int row = m0 + wm + i * 16 + quad * 4 + r;
        const int col = n0 + wn + j * 16 + lr;
        out[(size_t)row * D_MODEL + col] = acc[i][j][r];
      }
}

// ---------------------------------------------------------------------------
// Attention, S^T formulation. KV-tile = 64, DOUBLE-BUFFERED (T3+T4): prefetch
// tile t+1 while computing tile t; raw s_barrier + counted s_waitcnt vmcnt(6)
// (never 0 in the main loop) so staging latency hides under MFMA. T5 setprio
// around the PV cluster. T1 XCD-swizzle: all 16 q-tiles of a (b,h) land on
// one XCD -> K/V (768KB x 4 resident groups = 3MB) stays in the 4MB L2.
// Serial chunk structure: every Ps read is MFMA-consumed before the next Ps
// write (no outstanding-read WAR). VERIFIED at 74us attn / 3 passing runs.
// ---------------------------------------------------------------------------
__global__ __launch_bounds__(256) void attn_mfma_kernel(
    const ushort* __restrict__ Q, const ushort* __restrict__ Kb,
    const ushort* __restrict__ Vt, ushort* __restrict__ Oo) {
  __shared__ ushort Ks[2][64][64];   // [buf][kv][dk], 8x16B blocks, XOR-swz
  __shared__ ushort Vs[2][128][64];  // [buf][dv][kv], 8x16B blocks, XOR-swz
  __shared__ ushort Ps[4][32][36];   // per-wave [q][kv32 + pad]

  const int t = threadIdx.x;
  // XCD-aware bijective remap (nwg=512, 512%8==0): each XCD gets 4 full
  // (b,h) groups (16 q-tiles each) -> K/V L2-resident per XCD.
  const int n = blockIdx.x + 16 * blockIdx.y + 128 * blockIdx.z;
  const int l = (n & 7) * 64 + (n >> 3);
  const int qt = l & 15, h = (l >> 4) & 7, b = l >> 7;

  const int w = t >> 6, lane = t & 63;
  const int lr = lane & 15, quad = lane >> 4;
  const int q0 = qt * 128 + w * 32;
  const int swk = lr & 7;

  union { bf16x8 v; ushort u[8]; } one8;
#pragma unroll
  for (int i = 0; i < 8; ++i) one8.u[i] = 0x3F80;  // bf16 1.0

  bf16x8 aq[2][2];
#pragma unroll
  for (int mt = 0; mt < 2; ++mt)
#pragma unroll
    for (int kh = 0; kh < 2; ++kh)
      aq[mt][kh] = *(const bf16x8*)&Q[(size_t)(b * SQL + q0 + mt * 16 + lr) *
                                          (NH * DK) +
                                      h * DK + kh * 32 + quad * 8];

  f32x4 accO[2][9];
#pragma unroll
  for (int mt = 0; mt < 2; ++mt)
#pragma unroll
    for (int dn = 0; dn < 9; ++dn) accO[mt][dn] = (f32x4){0.f, 0.f, 0.f, 0.f};

  const ushort* kbase = Kb + (size_t)b * SKV * (NH * DK) + h * DK;
  const ushort* vbase = Vt + (size_t)(b * NH + h) * DV * SKV;

  // staging: rows of 64 ushorts = 8 x 16B blocks; 256 lanes cover 32 rows
  // per GLDS round. row = t>>3, phys blk = t&7, logical = phys ^ (row&7);
  // row&7 invariant across +32-row rounds.
  const int srow = t >> 3;
  const int sb7 = (t & 7) ^ (srow & 7);
  const ushort* gK = kbase + (size_t)srow * (NH * DK) + sb7 * 8;
  const ushort* gV = vbase + (size_t)srow * SKV + sb7 * 8;
  ushort* dK = (ushort*)Ks + t * 8;
  ushort* dV = (ushort*)Vs + t * 8;

  // K tile 64x64 = 2 rounds; V tile 128x64 = 4 rounds; 6 GLDS per tile.
  auto stage = [&](int kv0, int buf) {
    const ushort* gk = gK + (size_t)kv0 * (NH * DK);
    ushort* dk = dK + buf * 4096;
    GLDS16(gk, dk);
    GLDS16(gk + (size_t)32 * (NH * DK), dk + 2048);
    const ushort* gv = gV + kv0;
    ushort* dv = dV + buf * 8192;
    GLDS16(gv, dv);
    GLDS16(gv + (size_t)32 * SKV, dv + 2048);
    GLDS16(gv + (size_t)64 * SKV, dv + 4096);
    GLDS16(gv + (size_t)96 * SKV, dv + 6144);
  };

  // one 32-kv chunk: S^T -> exp2 -> pack to Ps -> A-frags -> PV (+rowsum)
  auto chunk = [&](const ushort(*Kc)[64], const ushort(*Vc)[64], int c) {
#pragma unroll
    for (int tt = 0; tt < 2; ++tt) {
      const int nt = c * 2 + tt;
      const bf16x8 fk0 = *(const bf16x8*)&Kc[nt * 16 + lr][(quad ^ swk) * 8];
      const bf16x8 fk1 =
          *(const bf16x8*)&Kc[nt * 16 + lr][((4 + quad) ^ swk) * 8];
#pragma unroll
      for (int mt = 0; mt < 2; ++mt) {
        f32x4 s = (f32x4){0.f, 0.f, 0.f, 0.f};
        s = MFMA16(fk0, aq[mt][0], s);
        s = MFMA16(fk1, aq[mt][1], s);
        const unsigned u0 = __float_as_uint(EXP2(s[0]));
        const unsigned u1 = __float_as_uint(EXP2(s[1]));
        const unsigned u2 = __float_as_uint(EXP2(s[2]));
        const unsigned u3 = __float_as_uint(EXP2(s[3]));
        uint2 dd;
        dd.x = __builtin_amdgcn_perm(u1, u0, 0x07060302u);
        dd.y = __builtin_amdgcn_perm(u3, u2, 0x07060302u);
        *(uint2*)&Ps[w][mt * 16 + lr][tt * 16 + quad * 4] = dd;
      }
    }
    bf16x8 ap[2];
#pragma unroll
    for (int mt = 0; mt < 2; ++mt) {
      union { bf16x8 v; uint2 u[2]; } fr;
      fr.u[0] = *(const uint2*)&Ps[w][mt * 16 + lr][quad * 8];
      fr.u[1] = *(const uint2*)&Ps[w][mt * 16 + lr][quad * 8 + 4];
      ap[mt] = fr.v;
    }
    __builtin_amdgcn_s_setprio(1);
#pragma unroll
    for (int dn = 0; dn < 8; ++dn) {
      const bf16x8 fv =
          *(const bf16x8*)&Vc[dn * 16 + lr][((c * 4 + quad) ^ swk) * 8];
      accO[0][dn] = MFMA16(ap[0], fv, accO[0][dn]);
      accO[1][dn] = MFMA16(ap[1], fv, accO[1][dn]);
    }
    accO[0][8] = MFMA16(ap[0], one8.v, accO[0][8]);
    accO[1][8] = MFMA16(ap[1], one8.v, accO[1][8]);
    __builtin_amdgcn_s_setprio(0);
  };

  stage(0, 0);
  for (int ti = 0; ti < 31; ++ti) {
    stage((ti + 1) * 64, (ti + 1) & 1);
    // tile ti's 6 loads retired (in-order); tile ti+1's 6 stay in flight
    asm volatile("s_waitcnt vmcnt(6)" ::: "memory");
    __builtin_amdgcn_s_barrier();
    __builtin_amdgcn_sched_barrier(0);
    const ushort(*Kc)[64] = Ks[ti & 1];
    const ushort(*Vc)[64] = Vs[ti & 1];
    chunk(Kc, Vc, 0);
    chunk(Kc, Vc, 1);
    __builtin_amdgcn_sched_barrier(0);
    __builtin_amdgcn_s_barrier();  // all waves done reading before overwrite
  }
  asm volatile("s_waitcnt vmcnt(0)" ::: "memory");
  __builtin_amdgcn_s_barrier();
  __builtin_amdgcn_sched_barrier(0);
  chunk(Ks[1], Vs[1], 0);
  chunk(Ks[1], Vs[1], 1);

  // ---- normalize: row sums already in C-layout at (quad, r) ----
#pragma unroll
  for (int mt = 0; mt < 2; ++mt) {
    float inv[4];
#pragma unroll
    for (int r = 0; r < 4; ++r) inv[r] = 1.f / accO[mt][8][r];
#pragma unroll
    for (int dn = 0; dn < 8; ++dn)
#pragma unroll
      for (int r = 0; r < 4; ++r) {
        const size_t row = (size_t)b * SQL + q0 + mt * 16 + quad * 4 + r;
        Oo[row * D_MODEL + h * DV + dn * 16 + lr] =
            f2bf(accO[mt][dn][r] * inv[r]);
      }
  }
}

// ---------------------------------------------------------------------------
// Workspace (ushorts): encb 8.39M | preb 8.39M | WqT .52M | WkT .52M |
// WvT 1.05M (contig Wqkv) | WoT 1.05M | qb 4.19M | kb 4.19M | vt 8.39M (~73MB)
// Alias: ao = encb (encb's last reader is gemm_qkv; attn writes after).
// ---------------------------------------------------------------------------
extern "C" void kernel_launch(void* const* d_in, const int* in_sizes, int n_in,
                              void* d_out, int out_size, void* d_ws,
                              size_t ws_size, hipStream_t stream) {
  const float* enc = (const float*)d_in[0];
  const float* pre = (const float*)d_in[1];
  const float* Wq = (const float*)d_in[2];
  const float* Wk = (const float*)d_in[3];
  const float* Wv = (const float*)d_in[4];
  const float* Wo = (const float*)d_in[5];
  float* out = (float*)d_out;

  const int M = BB * SQL;  // 8192

  ushort* encb = (ushort*)d_ws;
  ushort* preb = encb + (size_t)M * D_MODEL;
  ushort* WqT = preb + (size_t)M * D_MODEL;
  ushort* WkT = WqT + (size_t)(NH * DK) * D_MODEL;
  ushort* WvT = WkT + (size_t)(NH * DK) * D_MODEL;
  ushort* WoT = WvT + (size_t)D_MODEL * D_MODEL;
  ushort* qb = WoT + (size_t)D_MODEL * D_MODEL;
  ushort* kb = qb + (size_t)M * (NH * DK);
  ushort* vt = kb + (size_t)M * (NH * DK);
  ushort* ao = encb;  // alias

  const int n4 = M * D_MODEL / 4;
  dim3 blk(256);
  dim3 tblk(32, 8);

  cvt2_kernel<<<dim3(n4 / 256, 1, 2), blk, 0, stream>>>(enc, pre, encb, preb,
                                                        n4);
  cvt_t4_kernel<<<dim3(32, 32, 4), tblk, 0, stream>>>(Wq, Wk, Wv, Wo, WqT, WkT,
                                                      WvT, WoT);

  // fused q+k+v projection (+v transpose); q pre-scaled by log2e/sqrt(dk)
  gemm_qkv_kernel<<<dim3(16, 64), blk, 0, stream>>>(
      preb, encb, WqT, qb, kb, vt, 0.18033688011112042f);

  attn_mfma_kernel<<<dim3(SQL / 128, NH, BB), blk, 0, stream>>>(qb, kb, vt, ao);

  gemm_o_kernel<<<dim3(8, 64), blk, 0, stream>>>(ao, WoT, out);
}

// Round 8
// 248.533 us; speedup vs baseline: 1.1470x; 1.0212x over previous
//
#include <hip/hip_runtime.h>
#include <math.h>

#define D_MODEL 1024
#define DK 64
#define DV 128
#define NH 8
#define BB 4
#define SQL 2048
#define SKV 2048

typedef __bf16 bf16x8 __attribute__((ext_vector_type(8)));
typedef float f32x4 __attribute__((ext_vector_type(4)));

#if __has_builtin(__builtin_amdgcn_exp2f)
#define EXP2(x) __builtin_amdgcn_exp2f(x)
#else
#define EXP2(x) exp2f(x)
#endif

#define MFMA16(a, b, c) __builtin_amdgcn_mfma_f32_16x16x32_bf16(a, b, c, 0, 0, 0)

// fp32 -> bf16 round-to-nearest-even
__device__ __forceinline__ ushort f2bf(float f) {
  unsigned u = __float_as_uint(f);
  u += 0x7FFFu + ((u >> 16) & 1u);
  return (ushort)(u >> 16);
}
// pack two fp32 -> bf16x2 (RNE both halves)
__device__ __forceinline__ unsigned pk2bf(float lo, float hi) {
  unsigned ul = __float_as_uint(lo);
  unsigned uh = __float_as_uint(hi);
  ul += 0x7FFFu + ((ul >> 16) & 1u);
  uh += 0x7FFFu + ((uh >> 16) & 1u);
  return __builtin_amdgcn_perm(uh, ul, 0x07060302u);
}

// async global->LDS, 16B per lane; dest = wave-uniform base + lane*16
#define GLDS16(g, l)                                                       \
  __builtin_amdgcn_global_load_lds(                                        \
      (const __attribute__((address_space(1))) unsigned int*)(g),          \
      (__attribute__((address_space(3))) unsigned int*)(l), 16, 0, 0)

// ---------------------------------------------------------------------------
// fp32 -> bf16 elementwise, two tensors in one dispatch (z selects)
// ---------------------------------------------------------------------------
__global__ __launch_bounds__(256) void cvt2_kernel(
    const float* __restrict__ s0, const float* __restrict__ s1,
    ushort* __restrict__ d0, ushort* __restrict__ d1, int n4) {
  const float* src = blockIdx.z ? s1 : s0;
  ushort* dst = blockIdx.z ? d1 : d0;
  int i = blockIdx.x * 256 + threadIdx.x;
  if (i >= n4) return;
  float4 v = ((const float4*)src)[i];
  ushort4 o;
  o.x = f2bf(v.x); o.y = f2bf(v.y); o.z = f2bf(v.z); o.w = f2bf(v.w);
  ((ushort4*)dst)[i] = o;
}

// ---------------------------------------------------------------------------
// Four weight transposes (fp32 [1024][C] -> bf16 [C][1024]) in one dispatch.
// ---------------------------------------------------------------------------
__global__ __launch_bounds__(256) void cvt_t4_kernel(
    const float* __restrict__ W0, const float* __restrict__ W1,
    const float* __restrict__ W2, const float* __restrict__ W3,
    ushort* __restrict__ T0, ushort* __restrict__ T1, ushort* __restrict__ T2,
    ushort* __restrict__ T3) {
  __shared__ ushort T[32][34];
  const int z = blockIdx.z;
  const int C = (z < 2) ? 512 : 1024;
  const int c0 = blockIdx.y * 32;
  if (c0 >= C) return;
  const float* W = (z == 0) ? W0 : (z == 1) ? W1 : (z == 2) ? W2 : W3;
  ushort* Wt = (z == 0) ? T0 : (z == 1) ? T1 : (z == 2) ? T2 : T3;
  const int R = 1024;
  const int r0 = blockIdx.x * 32;
  const int tx = threadIdx.x, ty = threadIdx.y;
#pragma unroll
  for (int i = 0; i < 4; ++i) {
    const int rr = ty + i * 8;
    T[rr][tx] = f2bf(W[(size_t)(r0 + rr) * C + c0 + tx]);
  }
  __syncthreads();
#pragma unroll
  for (int i = 0; i < 4; ++i) {
    const int rr = ty + i * 8;
    Wt[(size_t)(c0 + rr) * R + r0 + tx] = T[tx][rr];
  }
}

// ---------------------------------------------------------------------------
// GEMM core: acc[4][4] = Atile[128,K] @ Bttile[128,K]^T (per-wave 64x64).
// T4 counted-vmcnt, 2-DEEP prefetch, 3 LDS buffers: at iter ti, stage tile
// ti+2 into buf (ti+2)%3, then s_waitcnt vmcnt(8) retires exactly tile ti's 4
// loads while 8 (tiles ti+1, ti+2) stay in flight across the barriers and the
// whole compute phase -> ~2 K-steps of latency coverage. Writer (ti+2)%3 ==
// reader buffer of iter ti-1, fenced by that iteration's end barrier.
// ---------------------------------------------------------------------------
__device__ __forceinline__ void gemm_core_acc(ushort* sh, const ushort* At,
                                              const ushort* Bt, int K,
                                              f32x4 (&acc)[4][4]) {
  const int t = threadIdx.x;
  const int w = t >> 6, lane = t & 63;
  const int wm = (w >> 1) * 64, wn = (w & 1) * 64;
  const int lr = lane & 15, quad = lane >> 4;

  const int r0 = t >> 2;
  const int lb = (t & 3) ^ ((r0 >> 1) & 3);
  const ushort* gA0 = At + (size_t)r0 * K + lb * 8;
  const ushort* gA1 = At + (size_t)(r0 + 64) * K + lb * 8;
  const ushort* gB0 = Bt + (size_t)r0 * K + lb * 8;
  const ushort* gB1 = Bt + (size_t)(r0 + 64) * K + lb * 8;

  const int sw = (quad ^ ((lr >> 1) & 3)) * 8;

#pragma unroll
  for (int i = 0; i < 4; ++i)
#pragma unroll
    for (int j = 0; j < 4; ++j) acc[i][j] = (f32x4){0.f, 0.f, 0.f, 0.f};

  auto stage = [&](int k0, int buf) {
    ushort* d = sh + buf * 8192 + t * 8;
    GLDS16(gA0 + k0, d);
    GLDS16(gA1 + k0, d + 2048);
    GLDS16(gB0 + k0, d + 4096);
    GLDS16(gB1 + k0, d + 6144);
  };

  const int NT = K >> 5;  // K-steps of 32
  stage(0, 0);
  stage(32, 1);
  for (int ti = 0; ti < NT; ++ti) {
    if (ti + 2 < NT) {
      stage((ti + 2) * 32, (ti + 2) % 3);
      asm volatile("s_waitcnt vmcnt(8)" ::: "memory");
    } else if (ti + 1 < NT) {
      asm volatile("s_waitcnt vmcnt(4)" ::: "memory");
    } else {
      asm volatile("s_waitcnt vmcnt(0)" ::: "memory");
    }
    __builtin_amdgcn_s_barrier();
    __builtin_amdgcn_sched_barrier(0);
    const ushort(*A)[32] = (const ushort(*)[32])(sh + (ti % 3) * 8192);
    const ushort(*B)[32] = (const ushort(*)[32])(sh + (ti % 3) * 8192 + 4096);
    bf16x8 fa[4], fb[4];
#pragma unroll
    for (int i = 0; i < 4; ++i) fa[i] = *(const bf16x8*)&A[wm + i * 16 + lr][sw];
#pragma unroll
    for (int j = 0; j < 4; ++j) fb[j] = *(const bf16x8*)&B[wn + j * 16 + lr][sw];
#pragma unroll
    for (int i = 0; i < 4; ++i)
#pragma unroll
      for (int j = 0; j < 4; ++j) acc[i][j] = MFMA16(fa[i], fb[j], acc[i][j]);
    __builtin_amdgcn_sched_barrier(0);
    if (ti + 1 < NT) __builtin_amdgcn_s_barrier();  // readers done pre-overwrite
  }
}

// ---------------------------------------------------------------------------
// Fused QKV projection + v-transpose. WqkvT = [2048][1024] (WqT|WkT|WvT).
// grid (16, 64), T1 XCD-swizzled: each XCD owns 8 contiguous m-panels x all
// 16 n-tiles -> A-panels L2-resident. n-region: q (pre-scaled), k, v
// (epilogue transposes into vt[bh][dv][skv] via per-wave LDS stage).
// shm union: 3-buf staging 48KB | v-epilogue 34.8KB -> 48KB, 3 blocks/CU.
// ---------------------------------------------------------------------------
__global__ __launch_bounds__(256) void gemm_qkv_kernel(
    const ushort* __restrict__ preb, const ushort* __restrict__ encb,
    const ushort* __restrict__ WqkvT, ushort* __restrict__ qb,
    ushort* __restrict__ kb, ushort* __restrict__ vt, float qsc) {
  __shared__ __attribute__((aligned(16))) ushort shm[24576];

  // bijective XCD remap (nwg=1024, %8==0): XCD k gets l in [128k,128(k+1))
  const int nlin = blockIdx.x + 16 * blockIdx.y;
  const int l = (nlin & 7) * 128 + (nlin >> 3);
  const int n0 = (l & 15) * 128, m0 = (l >> 4) * 128;

  const int t = threadIdx.x;
  const int w = t >> 6, lane = t & 63;
  const int wm = (w >> 1) * 64, wn = (w & 1) * 64;
  const int lr = lane & 15, quad = lane >> 4;

  const ushort* A = (n0 < 512) ? preb : encb;
  f32x4 acc[4][4];
  gemm_core_acc(shm, A + (size_t)m0 * D_MODEL, WqkvT + (size_t)n0 * D_MODEL,
                D_MODEL, acc);

  if (n0 < 1024) {
    ushort* C = (n0 < 512) ? qb : kb;
    const int ncol = (n0 < 512) ? n0 : n0 - 512;
    const float osc = (n0 < 512) ? qsc : 1.f;
#pragma unroll
    for (int i = 0; i < 4; ++i)
#pragma unroll
      for (int j = 0; j < 4; ++j)
#pragma unroll
        for (int r = 0; r < 4; ++r) {
          const int row = m0 + wm + i * 16 + quad * 4 + r;
          const int col = ncol + wn + j * 16 + lr;
          C[(size_t)row * 512 + col] = f2bf(acc[i][j][r] * osc);
        }
  } else {
    // v-region: tile = head h, batch b; write transposed into vt[bh][dv][skv]
    const int h = (n0 - 1024) >> 7;
    const int b = m0 >> 11;
    const int skv0 = m0 & 2047;
    __syncthreads();  // all waves done with staging LDS
    ushort(*Ep)[68] = (ushort(*)[68])(shm + w * 4352);  // per-wave [dv64][skv64+4]
#pragma unroll
    for (int i = 0; i < 4; ++i)
#pragma unroll
      for (int j = 0; j < 4; ++j) {
        uint2 dd;
        dd.x = pk2bf(acc[i][j][0], acc[i][j][1]);
        dd.y = pk2bf(acc[i][j][2], acc[i][j][3]);
        *(uint2*)&Ep[j * 16 + lr][i * 16 + quad * 4] = dd;
      }
    // per-wave region: no barrier needed before reading own Ep
    ushort* vbase =
        vt + ((size_t)(b * NH + h) * DV + wn) * SKV + skv0 + wm;
#pragma unroll
    for (int rep = 0; rep < 8; ++rep) {
      const int dvl = (lane >> 3) + rep * 8;
      const int skvc = (lane & 7) * 8;
      *(uint4*)&vbase[(size_t)dvl * SKV + skvc] = *(const uint4*)&Ep[dvl][skvc];
    }
  }
}

// ---------------------------------------------------------------------------
// Output projection: out fp32 [8192][1024] = ao @ WoT^T. grid (8, 64),
// T1 XCD-swizzled (nwg=512): XCD k owns m-panels 8k..8k+7.
// ---------------------------------------------------------------------------
__global__ __launch_bounds__(256) void gemm_o_kernel(
    const ushort* __restrict__ ao, const ushort* __restrict__ WoT,
    float* __restrict__ out) {
  __shared__ __attribute__((aligned(16))) ushort sh[24576];
  const int nlin = blockIdx.x + 8 * blockIdx.y;
  const int l = (nlin & 7) * 64 + (nlin >> 3);
  const int n0 = (l & 7) * 128, m0 = (l >> 3) * 128;
  const int t = threadIdx.x;
  const int w = t >> 6, lane = t & 63;
  const int wm = (w >> 1) * 64, wn = (w & 1) * 64;
  const int lr = lane & 15, quad = lane >> 4;
  f32x4 acc[4][4];
  gemm_core_acc(sh, ao + (size_t)m0 * D_MODEL, WoT + (size_t)n0 * D_MODEL,
                D_MODEL, acc);
#pragma unroll
  for (int i = 0; i < 4; ++i)
#pragma unroll
    for (int j = 0; j < 4; ++j)
#pragma unroll
      for (int r = 0; r < 4; ++r) {
        const int row = m0 + wm + i * 16 + quad * 4 + r;
        const int col = n0 + wn + j * 16 + lr;
        out[(size_t)row * D_MODEL + col] = acc[i][j][r];
      }
}

// ---------------------------------------------------------------------------
// Attention, S^T formulation. KV-tile = 64, DOUBLE-BUFFERED (T3+T4): prefetch
// tile t+1 while computing tile t; raw s_barrier + counted s_waitcnt vmcnt(6)
// (never 0 in the main loop) so staging latency hides under MFMA. T5 setprio
// around the PV cluster. T1 XCD-swizzle: all 16 q-tiles of a (b,h) land on
// one XCD -> K/V L2-resident per XCD. Ps-LDS chunk structure: every Ps read
// is MFMA-consumed before the next Ps write. VERIFIED 3x (74-85us attn).
// (R6's permlane in-register transpose FAILED correctness — reverted.)
// ---------------------------------------------------------------------------
__global__ __launch_bounds__(256) void attn_mfma_kernel(
    const ushort* __restrict__ Q, const ushort* __restrict__ Kb,
    const ushort* __restrict__ Vt, ushort* __restrict__ Oo) {
  __shared__ ushort Ks[2][64][64];   // [buf][kv][dk], 8x16B blocks, XOR-swz
  __shared__ ushort Vs[2][128][64];  // [buf][dv][kv], 8x16B blocks, XOR-swz
  __shared__ ushort Ps[4][32][36];   // per-wave [q][kv32 + pad]

  const int t = threadIdx.x;
  // XCD-aware bijective remap (nwg=512): each XCD gets 4 full (b,h) groups
  // (16 q-tiles each) -> K/V L2-resident per XCD.
  const int n = blockIdx.x + 16 * blockIdx.y + 128 * blockIdx.z;
  const int l = (n & 7) * 64 + (n >> 3);
  const int qt = l & 15, h = (l >> 4) & 7, b = l >> 7;

  const int w = t >> 6, lane = t & 63;
  const int lr = lane & 15, quad = lane >> 4;
  const int q0 = qt * 128 + w * 32;
  const int swk = lr & 7;

  union { bf16x8 v; ushort u[8]; } one8;
#pragma unroll
  for (int i = 0; i < 8; ++i) one8.u[i] = 0x3F80;  // bf16 1.0

  bf16x8 aq[2][2];
#pragma unroll
  for (int mt = 0; mt < 2; ++mt)
#pragma unroll
    for (int kh = 0; kh < 2; ++kh)
      aq[mt][kh] = *(const bf16x8*)&Q[(size_t)(b * SQL + q0 + mt * 16 + lr) *
                                          (NH * DK) +
                                      h * DK + kh * 32 + quad * 8];

  f32x4 accO[2][9];
#pragma unroll
  for (int mt = 0; mt < 2; ++mt)
#pragma unroll
    for (int dn = 0; dn < 9; ++dn) accO[mt][dn] = (f32x4){0.f, 0.f, 0.f, 0.f};

  const ushort* kbase = Kb + (size_t)b * SKV * (NH * DK) + h * DK;
  const ushort* vbase = Vt + (size_t)(b * NH + h) * DV * SKV;

  // staging: rows of 64 ushorts = 8 x 16B blocks; 256 lanes cover 32 rows
  // per GLDS round. row = t>>3, phys blk = t&7, logical = phys ^ (row&7).
  const int srow = t >> 3;
  const int sb7 = (t & 7) ^ (srow & 7);
  const ushort* gK = kbase + (size_t)srow * (NH * DK) + sb7 * 8;
  const ushort* gV = vbase + (size_t)srow * SKV + sb7 * 8;
  ushort* dK = (ushort*)Ks + t * 8;
  ushort* dV = (ushort*)Vs + t * 8;

  // K tile 64x64 = 2 rounds; V tile 128x64 = 4 rounds; 6 GLDS per tile.
  auto stage = [&](int kv0, int buf) {
    const ushort* gk = gK + (size_t)kv0 * (NH * DK);
    ushort* dk = dK + buf * 4096;
    GLDS16(gk, dk);
    GLDS16(gk + (size_t)32 * (NH * DK), dk + 2048);
    const ushort* gv = gV + kv0;
    ushort* dv = dV + buf * 8192;
    GLDS16(gv, dv);
    GLDS16(gv + (size_t)32 * SKV, dv + 2048);
    GLDS16(gv + (size_t)64 * SKV, dv + 4096);
    GLDS16(gv + (size_t)96 * SKV, dv + 6144);
  };

  // one 32-kv chunk: S^T -> exp2 -> pack to Ps -> A-frags -> PV (+rowsum)
  auto chunk = [&](const ushort(*Kc)[64], const ushort(*Vc)[64], int c) {
#pragma unroll
    for (int tt = 0; tt < 2; ++tt) {
      const int nt = c * 2 + tt;
      const bf16x8 fk0 = *(const bf16x8*)&Kc[nt * 16 + lr][(quad ^ swk) * 8];
      const bf16x8 fk1 =
          *(const bf16x8*)&Kc[nt * 16 + lr][((4 + quad) ^ swk) * 8];
#pragma unroll
      for (int mt = 0; mt < 2; ++mt) {
        f32x4 s = (f32x4){0.f, 0.f, 0.f, 0.f};
        s = MFMA16(fk0, aq[mt][0], s);
        s = MFMA16(fk1, aq[mt][1], s);
        const unsigned u0 = __float_as_uint(EXP2(s[0]));
        const unsigned u1 = __float_as_uint(EXP2(s[1]));
        const unsigned u2 = __float_as_uint(EXP2(s[2]));
        const unsigned u3 = __float_as_uint(EXP2(s[3]));
        uint2 dd;
        dd.x = __builtin_amdgcn_perm(u1, u0, 0x07060302u);
        dd.y = __builtin_amdgcn_perm(u3, u2, 0x07060302u);
        *(uint2*)&Ps[w][mt * 16 + lr][tt * 16 + quad * 4] = dd;
      }
    }
    bf16x8 ap[2];
#pragma unroll
    for (int mt = 0; mt < 2; ++mt) {
      union { bf16x8 v; uint2 u[2]; } fr;
      fr.u[0] = *(const uint2*)&Ps[w][mt * 16 + lr][quad * 8];
      fr.u[1] = *(const uint2*)&Ps[w][mt * 16 + lr][quad * 8 + 4];
      ap[mt] = fr.v;
    }
    __builtin_amdgcn_s_setprio(1);
#pragma unroll
    for (int dn = 0; dn < 8; ++dn) {
      const bf16x8 fv =
          *(const bf16x8*)&Vc[dn * 16 + lr][((c * 4 + quad) ^ swk) * 8];
      accO[0][dn] = MFMA16(ap[0], fv, accO[0][dn]);
      accO[1][dn] = MFMA16(ap[1], fv, accO[1][dn]);
    }
    accO[0][8] = MFMA16(ap[0], one8.v, accO[0][8]);
    accO[1][8] = MFMA16(ap[1], one8.v, accO[1][8]);
    __builtin_amdgcn_s_setprio(0);
  };

  stage(0, 0);
  for (int ti = 0; ti < 31; ++ti) {
    stage((ti + 1) * 64, (ti + 1) & 1);
    // tile ti's 6 loads retired (in-order); tile ti+1's 6 stay in flight
    asm volatile("s_waitcnt vmcnt(6)" ::: "memory");
    __builtin_amdgcn_s_barrier();
    __builtin_amdgcn_sched_barrier(0);
    const ushort(*Kc)[64] = Ks[ti & 1];
    const ushort(*Vc)[64] = Vs[ti & 1];
    chunk(Kc, Vc, 0);
    chunk(Kc, Vc, 1);
    __builtin_amdgcn_sched_barrier(0);
    __builtin_amdgcn_s_barrier();  // all waves done reading before overwrite
  }
  asm volatile("s_waitcnt vmcnt(0)" ::: "memory");
  __builtin_amdgcn_s_barrier();
  __builtin_amdgcn_sched_barrier(0);
  chunk(Ks[1], Vs[1], 0);
  chunk(Ks[1], Vs[1], 1);

  // ---- normalize: row sums already in C-layout at (quad, r) ----
#pragma unroll
  for (int mt = 0; mt < 2; ++mt) {
    float inv[4];
#pragma unroll
    for (int r = 0; r < 4; ++r) inv[r] = 1.f / accO[mt][8][r];
#pragma unroll
    for (int dn = 0; dn < 8; ++dn)
#pragma unroll
      for (int r = 0; r < 4; ++r) {
        const size_t row = (size_t)b * SQL + q0 + mt * 16 + quad * 4 + r;
        Oo[row * D_MODEL + h * DV + dn * 16 + lr] =
            f2bf(accO[mt][dn][r] * inv[r]);
      }
  }
}

// ---------------------------------------------------------------------------
// Workspace (ushorts): encb 8.39M | preb 8.39M | WqT .52M | WkT .52M |
// WvT 1.05M (contig Wqkv) | WoT 1.05M | qb 4.19M | kb 4.19M | vt 8.39M (~73MB)
// Alias: ao = encb (encb's last reader is gemm_qkv; attn writes after).
// ---------------------------------------------------------------------------
extern "C" void kernel_launch(void* const* d_in, const int* in_sizes, int n_in,
                              void* d_out, int out_size, void* d_ws,
                              size_t ws_size, hipStream_t stream) {
  const float* enc = (const float*)d_in[0];
  const float* pre = (const float*)d_in[1];
  const float* Wq = (const float*)d_in[2];
  const float* Wk = (const float*)d_in[3];
  const float* Wv = (const float*)d_in[4];
  const float* Wo = (const float*)d_in[5];
  float* out = (float*)d_out;

  const int M = BB * SQL;  // 8192

  ushort* encb = (ushort*)d_ws;
  ushort* preb = encb + (size_t)M * D_MODEL;
  ushort* WqT = preb + (size_t)M * D_MODEL;
  ushort* WkT = WqT + (size_t)(NH * DK) * D_MODEL;
  ushort* WvT = WkT + (size_t)(NH * DK) * D_MODEL;
  ushort* WoT = WvT + (size_t)D_MODEL * D_MODEL;
  ushort* qb = WoT + (size_t)D_MODEL * D_MODEL;
  ushort* kb = qb + (size_t)M * (NH * DK);
  ushort* vt = kb + (size_t)M * (NH * DK);
  ushort* ao = encb;  // alias

  const int n4 = M * D_MODEL / 4;
  dim3 blk(256);
  dim3 tblk(32, 8);

  cvt2_kernel<<<dim3(n4 / 256, 1, 2), blk, 0, stream>>>(enc, pre, encb, preb,
                                                        n4);
  cvt_t4_kernel<<<dim3(32, 32, 4), tblk, 0, stream>>>(Wq, Wk, Wv, Wo, WqT, WkT,
                                                      WvT, WoT);

  // fused q+k+v projection (+v transpose); q pre-scaled by log2e/sqrt(dk)
  gemm_qkv_kernel<<<dim3(16, 64), blk, 0, stream>>>(
      preb, encb, WqT, qb, kb, vt, 0.18033688011112042f);

  attn_mfma_kernel<<<dim3(SQL / 128, NH, BB), blk, 0, stream>>>(qb, kb, vt, ao);

  gemm_o_kernel<<<dim3(8, 64), blk, 0, stream>>>(ao, WoT, out);
}